// Round 11
// baseline (2405.799 us; speedup 1.0000x reference)
//
#include <hip/hip_runtime.h>
#include <hip/hip_fp16.h>
#include <hip/hip_cooperative_groups.h>
#include <math.h>

namespace cg = cooperative_groups;

#define WW 256
#define HH 256
#define DDP 96
#define HWP (WW*HH)
#define DHW (DDP*HWP)
#define N2 (2*DHW)
#define N4 (4*DHW)
#define NT 256
#define RED_BLOCKS 1024
#define NITER 40

// legacy (fallback) tiling
#define TX 64
#define TY 8
#define ZS 12
#define NSLAB (DDP/ZS)          // 8
#define RPAIRS 34

// cooperative tiling: 64 x 16 x 12 tile, 2 px-pairs per thread
#define CTY 16
#define CZS 12
#define CNSLAB (DDP/CZS)        // 8
#define CRP 34                  // staged u32 pairs per row (px x0-2..x0+65)
#define CPAD 35                 // padded row stride (bank spread)
#define COOP_BPCU 8             // required blocks/CU for co-residency (2048 total)

typedef unsigned int u32;
typedef unsigned short u16;
typedef __half2 h2;

__device__ __forceinline__ float sigm(float x){return 1.f/(1.f+expf(-x));}
__device__ __forceinline__ int   icl(int v,int hi){return min(max(v,0),hi);}
__device__ __forceinline__ u32 h2u(h2 v){return __builtin_bit_cast(u32,v);}
__device__ __forceinline__ h2  u2h(u32 v){return __builtin_bit_cast(h2,v);}
__device__ __forceinline__ float2 up2(u32 v){return __half22float2(u2h(v));}
__device__ __forceinline__ u32 dn2(float a,float b){return h2u(__floats2half2_rn(a,b));}
__device__ __forceinline__ u32 pmin2(u32 a,u32 b){u32 d;asm("v_pk_min_f16 %0, %1, %2":"=v"(d):"v"(a),"v"(b));return d;}
__device__ __forceinline__ u32 pmax2(u32 a,u32 b){u32 d;asm("v_pk_max_f16 %0, %1, %2":"=v"(d):"v"(a),"v"(b));return d;}
__device__ __forceinline__ u32 shpair(u32 hiSrc,u32 loSrc){return __builtin_amdgcn_alignbit(hiSrc,loSrc,16);}
#define INF2P 0x7C007C00u
#define INF2N 0xFC00FC00u

// ====================== cooperative persistent path ======================

struct CCtx {
    int ty, x0, y0, z0;
    int gxc, gyc, w0;
    size_t base;
    const float* fin;
    bool dosig;
};

__device__ __forceinline__ void cstageH(const CCtx& c, const u16* __restrict__ src, int zi,
                                        u32 (*raw)[CTY+2][CPAD], int b) {
    if ((unsigned)zi >= DDP) return;
    const u16* pl = src + c.base + (size_t)zi * HWP;
    for (int idx = threadIdx.x; idx < (CTY+2)*CRP; idx += NT) {
        int r = idx / CRP, w = idx - r*CRP;
        const u16* rp = pl + (size_t)icl(c.y0-1+r, HH-1) * WW;
        int gx0 = c.x0 - 2 + 2*w;
        u32 v;
        if (gx0 < 0)        { u32 t2 = rp[0];    v = t2 | (t2<<16); }
        else if (gx0 >= WW) { u32 t2 = rp[WW-1]; v = t2 | (t2<<16); }
        else v = *(const u32*)(rp + gx0);
        raw[b][r][w] = v;
    }
}

__device__ __forceinline__ void cstageF(const CCtx& c, int zi,
                                        u32 (*raw)[CTY+2][CPAD], int b) {
    if ((unsigned)zi >= DDP) return;
    const float* pl = c.fin + (size_t)zi * HWP;
    for (int idx = threadIdx.x; idx < (CTY+2)*CRP; idx += NT) {
        int r = idx / CRP, w = idx - r*CRP;
        const float* rp = pl + (size_t)icl(c.y0-1+r, HH-1) * WW;
        int gx0 = c.x0 - 2 + 2*w;
        float v0, v1;
        if (gx0 < 0)        { v0 = v1 = rp[0]; }
        else if (gx0 >= WW) { v0 = v1 = rp[WW-1]; }
        else { float2 fv = *(const float2*)(rp + gx0); v0 = fv.x; v1 = fv.y; }
        raw[b][r][w] = dn2(v0, v1);
    }
}

// 3x3 xy window (min and optionally max) for 2 adjacent output pairs.
__device__ __forceinline__ void cwindow(u32 (*raw)[CTY+2][CPAD], int b, int ty, int wl,
                                        u32& xn0, u32& xn1, u32& xm0, u32& xm1, bool domax) {
    u32 rn0 = INF2P, rn1 = INF2P, rm0 = INF2N, rm1 = INF2N;
    #pragma unroll
    for (int dr = 0; dr < 3; ++dr) {
        const u32* rp = &raw[b][ty+dr][wl];
        u32 L = rp[0], M0 = rp[1], M1 = rp[2], R = rp[3];
        u32 ls0 = shpair(M0, L), rs0 = shpair(M1, M0), rs1 = shpair(R, M1);
        rn0 = pmin2(rn0, pmin2(M0, pmin2(ls0, rs0)));
        rn1 = pmin2(rn1, pmin2(M1, pmin2(rs0, rs1)));
        if (domax) {
            rm0 = pmax2(rm0, pmax2(M0, pmax2(ls0, rs0)));
            rm1 = pmax2(rm1, pmax2(M1, pmax2(rs0, rs1)));
        }
    }
    xn0 = rn0; xn1 = rn1; xm0 = rm0; xm1 = rm1;
}

// Phase A: EB = e_1 = E(f(x)) (sigmoid fused at write for pred vols)
__device__ void cphaseA(const CCtx& c, u16* __restrict__ EB, u32 (*raw)[CTY+2][CPAD]) {
    u32 a0n0=INF2P,a1n0=INF2P,a2n0=INF2P, a0n1=INF2P,a1n1=INF2P,a2n1=INF2P;
    cstageF(c, c.z0-1, raw, 0);
    __syncthreads();
    #pragma unroll
    for (int s = 0; s <= CZS+1; ++s) {
        const int zi = c.z0 - 1 + s;
        if (s <= CZS) cstageF(c, zi+1, raw, (s+1)&1);
        u32 xn0=INF2P, xn1=INF2P, xm0, xm1;
        if ((unsigned)zi < DDP) cwindow(raw, s&1, c.ty, c.w0, xn0, xn1, xm0, xm1, false);
        a0n0=a1n0; a1n0=a2n0; a2n0=xn0;  a0n1=a1n1; a1n1=a2n1; a2n1=xn1;
        if (s >= 2) {
            const int zc = c.z0 + s - 2;
            size_t gidx = c.base + (size_t)zc*HWP + (size_t)c.gyc*WW + c.gxc;
            u32 e0 = pmin2(a0n0, pmin2(a1n0, a2n0));
            u32 e1 = pmin2(a0n1, pmin2(a1n1, a2n1));
            if (c.dosig) {
                float2 f0 = up2(e0), f1 = up2(e1);
                e0 = dn2(sigm(f0.x), sigm(f0.y));
                e1 = dn2(sigm(f1.x), sigm(f1.y));
            }
            *(u32*)(EB + gidx) = e0;
            *(u32*)(EB + gidx + 2) = e1;
        }
        __syncthreads();
    }
}

// Update phase. M: 0 = first (skel init, av from fp32 input), 1 = mid, 2 = last (write SKEL).
template<int M>
__device__ void cphaseU(const CCtx& c, const u16* __restrict__ halo, u16* __restrict__ cen,
                        u16* __restrict__ SKEL, u32 (&skl)[CZS][2], u32 (*raw)[CTY+2][CPAD]) {
    u32 a0n0=INF2P,a1n0=INF2P,a2n0=INF2P, a0n1=INF2P,a1n1=INF2P,a2n1=INF2P;
    u32 a0m0=INF2N,a1m0=INF2N,a2m0=INF2N, a0m1=INF2N,a1m1=INF2N,a2m1=INF2N;
    cstageH(c, halo, c.z0-1, raw, 0);
    __syncthreads();
    #pragma unroll
    for (int s = 0; s <= CZS+1; ++s) {
        const int zi = c.z0 - 1 + s;
        if (s <= CZS) cstageH(c, halo, zi+1, raw, (s+1)&1);
        u32 xn0=INF2P, xn1=INF2P, xm0=INF2N, xm1=INF2N;
        if ((unsigned)zi < DDP) cwindow(raw, s&1, c.ty, c.w0, xn0, xn1, xm0, xm1, true);
        a0n0=a1n0; a1n0=a2n0; a2n0=xn0;  a0n1=a1n1; a1n1=a2n1; a2n1=xn1;
        a0m0=a1m0; a1m0=a2m0; a2m0=xm0;  a0m1=a1m1; a1m1=a2m1; a2m1=xm1;
        if (s >= 2) {
            const int zr = s - 2;
            const int zc = c.z0 + zr;
            size_t voff = (size_t)zc*HWP + (size_t)c.gyc*WW + c.gxc;
            size_t gidx = c.base + voff;
            float2 m0 = up2(pmax2(a0m0, pmax2(a1m0, a2m0)));
            float2 m1 = up2(pmax2(a0m1, pmax2(a1m1, a2m1)));
            float av0, av1, av2, av3;
            if (M == 0) {
                float4 fv = *(const float4*)(c.fin + voff);
                av0=fv.x; av1=fv.y; av2=fv.z; av3=fv.w;
                if (c.dosig) { av0=sigm(av0); av1=sigm(av1); av2=sigm(av2); av3=sigm(av3); }
            } else {
                float2 c0 = up2(*(const u32*)(cen + gidx));
                float2 c1 = up2(*(const u32*)(cen + gidx + 2));
                av0=c0.x; av1=c0.y; av2=c1.x; av3=c1.y;
            }
            float d0 = fmaxf(av0 - m0.x, 0.f);
            float d1 = fmaxf(av1 - m0.y, 0.f);
            float d2 = fmaxf(av2 - m1.x, 0.f);
            float d3 = fmaxf(av3 - m1.y, 0.f);
            if (M == 0) {
                skl[zr][0] = dn2(d0, d1);
                skl[zr][1] = dn2(d2, d3);
            } else {
                float2 s0 = up2(skl[zr][0]);
                float2 s1 = up2(skl[zr][1]);
                s0.x += fmaxf(d0 - s0.x*d0, 0.f);
                s0.y += fmaxf(d1 - s0.y*d1, 0.f);
                s1.x += fmaxf(d2 - s1.x*d2, 0.f);
                s1.y += fmaxf(d3 - s1.y*d3, 0.f);
                skl[zr][0] = dn2(s0.x, s0.y);
                skl[zr][1] = dn2(s1.x, s1.y);
            }
            if (M != 2) {
                u32 e0 = pmin2(a0n0, pmin2(a1n0, a2n0));
                u32 e1 = pmin2(a0n1, pmin2(a1n1, a2n1));
                *(u32*)(cen + gidx) = e0;
                *(u32*)(cen + gidx + 2) = e1;
            } else {
                *(u32*)(SKEL + gidx) = skl[zr][0];
                *(u32*)(SKEL + gidx + 2) = skl[zr][1];
            }
        }
        __syncthreads();
    }
}

__global__ __launch_bounds__(NT, COOP_BPCU) void coop_kernel(const float* __restrict__ ypred,
                                                             const float* __restrict__ ytrue,
                                                             u16* __restrict__ EA,
                                                             u16* __restrict__ EB,
                                                             u16* __restrict__ SKEL) {
    cg::grid_group g = cg::this_grid();
    CCtx c;
    const int tx = threadIdx.x & 15;
    c.ty = threadIdx.x >> 4;
    c.x0 = blockIdx.x * 64;
    c.y0 = blockIdx.y * CTY;
    const int vol = blockIdx.z / CNSLAB;
    c.z0 = (blockIdx.z % CNSLAB) * CZS;
    c.base = (size_t)vol * DHW;
    c.dosig = vol < 2;
    c.fin = c.dosig ? (ypred + c.base) : (ytrue + (size_t)(vol-2)*DHW);
    c.gxc = c.x0 + 4*tx;
    c.gyc = c.y0 + c.ty;
    c.w0 = 2*tx;

    __shared__ u32 raw[2][CTY+2][CPAD];
    u32 skl[CZS][2];

    cphaseA(c, EB, raw);                     // EB = e_1
    g.sync();
    cphaseU<0>(c, EB, EA, SKEL, skl, raw);   // skel init (iter 0); EA = e_2
    g.sync();
    for (int t = 1; t < NITER; ++t) {
        const u16* halo = (t & 1) ? EA : EB;
        u16* cen        = (t & 1) ? EB : EA;
        cphaseU<1>(c, halo, cen, SKEL, skl, raw);
        g.sync();
    }
    cphaseU<2>(c, EB, EA, SKEL, skl, raw);   // iter 40: halo e_41(EB), write skl -> SKEL
}

// ====================== legacy fallback path (round-10, proven) ======================

template<int MODE>
__global__ __launch_bounds__(NT) void step_kernel(const u16* __restrict__ ghalo,
                                                  u16* __restrict__ eaw,
                                                  const float* __restrict__ ypred,
                                                  const float* __restrict__ ytrue,
                                                  u16* __restrict__ skel) {
    const int tx2 = threadIdx.x & 31;
    const int ty  = threadIdx.x >> 5;
    const int x0 = blockIdx.x * TX;
    const int y0 = blockIdx.y * TY;
    const int vol = blockIdx.z / NSLAB;
    const int z0 = (blockIdx.z % NSLAB) * ZS;
    const size_t base = (size_t)vol * DHW;
    const int gxc = x0 + 2*tx2;
    const int gyc = y0 + ty;

    const float* fin = nullptr;
    bool dosig = false;
    if (MODE == 0 || MODE == 1) {
        if (vol < 2) { fin = ypred + base; dosig = true; }
        else         { fin = ytrue + (size_t)(vol-2)*DHW; }
    }

    __shared__ u32 raw[2][TY+2][RPAIRS];

    auto stage = [&](int zi, int buf) {
        if ((unsigned)zi >= DDP) return;
        if (MODE == 0) {
            const float* pl = fin + (size_t)zi * HWP;
            for (int idx = threadIdx.x; idx < (TY+2)*RPAIRS; idx += NT) {
                int r = idx / RPAIRS;
                int w = idx - r*RPAIRS;
                const float* rp = pl + (size_t)icl(y0-1+r, HH-1) * WW;
                int gx0 = x0 - 2 + 2*w;
                float v0, v1;
                if (gx0 < 0)        { v0 = v1 = rp[0]; }
                else if (gx0 >= WW) { v0 = v1 = rp[WW-1]; }
                else { float2 fv = *(const float2*)(rp + gx0); v0 = fv.x; v1 = fv.y; }
                raw[buf][r][w] = dn2(v0, v1);
            }
        } else {
            const u16* pl = ghalo + base + (size_t)zi * HWP;
            for (int idx = threadIdx.x; idx < (TY+2)*RPAIRS; idx += NT) {
                int r = idx / RPAIRS;
                int w = idx - r*RPAIRS;
                const u16* rp = pl + (size_t)icl(y0-1+r, HH-1) * WW;
                int gx0 = x0 - 2 + 2*w;
                u32 v;
                if (gx0 < 0)        { u32 t = rp[0];    v = t | (t<<16); }
                else if (gx0 >= WW) { u32 t = rp[WW-1]; v = t | (t<<16); }
                else v = *(const u32*)(rp + gx0);
                raw[buf][r][w] = v;
            }
        }
    };

    const int w0 = tx2 + 1;
    u32 nr0,nr1,nr2, mr0,mr1,mr2;
    nr0 = nr1 = nr2 = INF2P;
    mr0 = mr1 = mr2 = INF2N;

    stage(z0-1, (z0-1)&1);
    __syncthreads();

    for (int zi = z0-1; zi <= z0+ZS; ++zi) {
        if (zi < z0+ZS) stage(zi+1, (zi+1)&1);

        u32 axn = INF2P;
        u32 axm = INF2N;
        if ((unsigned)zi < DDP) {
            const int b = zi & 1;
            u32 La = raw[b][ty  ][w0-1], Ma = raw[b][ty  ][w0], Ra = raw[b][ty  ][w0+1];
            u32 Lb = raw[b][ty+1][w0-1], Mb = raw[b][ty+1][w0], Rb = raw[b][ty+1][w0+1];
            u32 Lc = raw[b][ty+2][w0-1], Mc = raw[b][ty+2][w0], Rc = raw[b][ty+2][w0+1];
            u32 lsa = shpair(Ma, La), rsa = shpair(Ra, Ma);
            u32 lsb = shpair(Mb, Lb), rsb = shpair(Rb, Mb);
            u32 lsc = shpair(Mc, Lc), rsc = shpair(Rc, Mc);
            u32 na = pmin2(Ma, pmin2(lsa, rsa));
            u32 nb = pmin2(Mb, pmin2(lsb, rsb));
            u32 nc = pmin2(Mc, pmin2(lsc, rsc));
            axn = pmin2(na, pmin2(nb, nc));
            if (MODE != 0) {
                u32 xa = pmax2(Ma, pmax2(lsa, rsa));
                u32 xb = pmax2(Mb, pmax2(lsb, rsb));
                u32 xc = pmax2(Mc, pmax2(lsc, rsc));
                axm = pmax2(xa, pmax2(xb, xc));
            }
        }
        nr0 = nr1; nr1 = nr2; nr2 = axn;
        if (MODE != 0) { mr0 = mr1; mr1 = mr2; mr2 = axm; }

        if (zi >= z0+1) {
            const int zc = zi - 1;
            size_t voff = (size_t)zc*HWP + (size_t)gyc*WW + gxc;
            size_t idx = base + voff;
            u32 e2 = pmin2(nr0, pmin2(nr1, nr2));
            if (MODE == 0) {
                if (dosig) {
                    float2 f = up2(e2);
                    e2 = dn2(sigm(f.x), sigm(f.y));
                }
                *(u32*)(eaw + idx) = e2;
            } else {
                float2 m = up2(pmax2(mr0, pmax2(mr1, mr2)));
                float av0, av1;
                if (MODE == 1) {
                    float2 fv = *(const float2*)(fin + voff);
                    av0 = fv.x; av1 = fv.y;
                    if (dosig) { av0 = sigm(av0); av1 = sigm(av1); }
                } else {
                    float2 a2 = up2(*(const u32*)(eaw + idx));
                    av0 = a2.x; av1 = a2.y;
                }
                float d0 = fmaxf(av0 - m.x, 0.f);
                float d1 = fmaxf(av1 - m.y, 0.f);
                u32 pk;
                if (MODE == 1) {
                    pk = dn2(d0, d1);
                } else {
                    float2 s = up2(*(const u32*)(skel + idx));
                    s.x += fmaxf(d0 - s.x*d0, 0.f);
                    s.y += fmaxf(d1 - s.y*d1, 0.f);
                    pk = dn2(s.x, s.y);
                }
                *(u32*)(skel + idx) = pk;
                if (MODE != 3) *(u32*)(eaw + idx) = e2;
            }
        }
        __syncthreads();
    }
}

// ====================== reductions ======================

__global__ __launch_bounds__(256) void reduce4_kernel(const u16* __restrict__ skel,
                                                      const float* __restrict__ ytrue,
                                                      const float* __restrict__ ypred,
                                                      float* __restrict__ part) {
    const u32* sp = (const u32*)skel;
    const u32* st = (const u32*)(skel + N2);
    const float2* yt = (const float2*)ytrue;
    const float2* yp = (const float2*)ypred;
    float a0=0.f,a1=0.f,a2=0.f,a3=0.f;
    for (int i = blockIdx.x*256 + threadIdx.x; i < N2/2; i += gridDim.x*256) {
        float2 s = up2(sp[i]);
        float2 u = up2(st[i]);
        float2 t = yt[i]; float2 q = yp[i];
        a0 += s.x*t.x + s.y*t.y;
        a1 += s.x + s.y;
        a2 += u.x*sigm(q.x) + u.y*sigm(q.y);
        a3 += u.x + u.y;
    }
    for (int off=32; off>0; off>>=1) {
        a0+=__shfl_down(a0,off); a1+=__shfl_down(a1,off);
        a2+=__shfl_down(a2,off); a3+=__shfl_down(a3,off);
    }
    __shared__ float red[4][4];
    int wave = threadIdx.x>>6;
    if ((threadIdx.x&63)==0){red[wave][0]=a0;red[wave][1]=a1;red[wave][2]=a2;red[wave][3]=a3;}
    __syncthreads();
    if (threadIdx.x==0){
        float s0=0,s1=0,s2=0,s3=0;
        for(int w=0;w<4;++w){s0+=red[w][0];s1+=red[w][1];s2+=red[w][2];s3+=red[w][3];}
        part[0*RED_BLOCKS+blockIdx.x]=s0; part[1*RED_BLOCKS+blockIdx.x]=s1;
        part[2*RED_BLOCKS+blockIdx.x]=s2; part[3*RED_BLOCKS+blockIdx.x]=s3;
    }
}

__global__ __launch_bounds__(256) void finalize_kernel(const float* __restrict__ part,
                                                       float* __restrict__ out) {
    float a0=0.f,a1=0.f,a2=0.f,a3=0.f;
    for (int i=threadIdx.x;i<RED_BLOCKS;i+=256){
        a0+=part[0*RED_BLOCKS+i]; a1+=part[1*RED_BLOCKS+i];
        a2+=part[2*RED_BLOCKS+i]; a3+=part[3*RED_BLOCKS+i];
    }
    for (int off=32; off>0; off>>=1){
        a0+=__shfl_down(a0,off); a1+=__shfl_down(a1,off);
        a2+=__shfl_down(a2,off); a3+=__shfl_down(a3,off);
    }
    __shared__ float red[4][4];
    int wave = threadIdx.x>>6;
    if ((threadIdx.x&63)==0){red[wave][0]=a0;red[wave][1]=a1;red[wave][2]=a2;red[wave][3]=a3;}
    __syncthreads();
    if (threadIdx.x==0){
        float s0=0,s1=0,s2=0,s3=0;
        for(int w=0;w<4;++w){s0+=red[w][0];s1+=red[w][1];s2+=red[w][2];s3+=red[w][3];}
        float tprec=(s0+1.f)/(s1+1.f);
        float tsens=(s2+1.f)/(s3+1.f);
        float cl2=2.f*tprec*tsens/(tprec+tsens+1.f);
        out[0]=1.f-cl2;
    }
}

__global__ void sentinel_kernel(float* out, float v){ out[0]=v; }

// ====================== launch ======================

extern "C" void kernel_launch(void* const* d_in, const int* in_sizes, int n_in,
                              void* d_out, int out_size, void* d_ws, size_t ws_size,
                              hipStream_t stream) {
    const float* ypred = (const float*)d_in[0];
    const float* ytrue = (const float*)d_in[1];
    float* out = (float*)d_out;

    const size_t need = (size_t)3*N4*sizeof(u16) + (size_t)4*RED_BLOCKS*sizeof(float);
    if (ws_size < need) { sentinel_kernel<<<1,1,0,stream>>>(out,-111111.f); return; }

    u16* EA   = (u16*)d_ws;
    u16* EB   = EA + N4;
    u16* SKEL = EB + N4;
    float* PART = (float*)(SKEL + N4);

    // Co-residency check for the cooperative path (deterministic across calls).
    int bpcu = 0;
    (void)hipOccupancyMaxActiveBlocksPerMultiprocessor(&bpcu, coop_kernel, NT, 0);

    if (bpcu >= COOP_BPCU) {
        void* args[] = { (void*)&ypred, (void*)&ytrue, (void*)&EA, (void*)&EB, (void*)&SKEL };
        dim3 cgrid(WW/64, HH/CTY, 4*CNSLAB);   // 4 x 16 x 32 = 2048 blocks
        (void)hipLaunchCooperativeKernel((const void*)coop_kernel, cgrid, dim3(NT),
                                         args, 0, stream);
    } else {
        // legacy 42-dispatch path (round-10, proven)
        dim3 grid(WW/TX, HH/TY, 4*NSLAB);   // 4 x 32 x 32 = 4096 blocks
        step_kernel<0><<<grid, NT, 0, stream>>>(nullptr, EB, ypred, ytrue, nullptr);
        step_kernel<1><<<grid, NT, 0, stream>>>(EB, EA, ypred, ytrue, SKEL);
        u16* h = EA;
        u16* a = EB;
        for (int t = 1; t <= NITER; ++t) {
            if (t < NITER) step_kernel<2><<<grid, NT, 0, stream>>>(h, a, nullptr, nullptr, SKEL);
            else           step_kernel<3><<<grid, NT, 0, stream>>>(h, a, nullptr, nullptr, SKEL);
            u16* tmp = h; h = a; a = tmp;
        }
    }

    reduce4_kernel<<<RED_BLOCKS, 256, 0, stream>>>(SKEL, ytrue, ypred, PART);
    finalize_kernel<<<1, 256, 0, stream>>>(PART, out);
}

// Round 12
// 2078.097 us; speedup vs baseline: 1.1577x; 1.1577x over previous
//
#include <hip/hip_runtime.h>
#include <hip/hip_fp16.h>
#include <math.h>

#define WW 256
#define HH 256
#define DDP 96
#define HWP (WW*HH)
#define DHW (DDP*HWP)
#define N2 (2*DHW)
#define N4 (4*DHW)
#define TX 128                  // 32 lanes x 2 px-pairs (4 px) per lane
#define TY 8
#define NT 256
#define ZS 12
#define NSLAB (DDP/ZS)          // 8
#define RED_BLOCKS 1024
#define NITER 40
#define RPAIRS 66               // staged u32 pairs per row: px x0-2 .. x0+129

typedef unsigned int u32;
typedef unsigned short u16;
typedef __half2 h2;

__device__ __forceinline__ float sigm(float x){return 1.f/(1.f+expf(-x));}
__device__ __forceinline__ int   icl(int v,int hi){return min(max(v,0),hi);}
__device__ __forceinline__ u32 h2u(h2 v){return __builtin_bit_cast(u32,v);}
__device__ __forceinline__ h2  u2h(u32 v){return __builtin_bit_cast(h2,v);}
__device__ __forceinline__ float2 up2(u32 v){return __half22float2(u2h(v));}
__device__ __forceinline__ u32 dn2(float a,float b){return h2u(__floats2half2_rn(a,b));}
__device__ __forceinline__ u32 pmin2(u32 a,u32 b){u32 d;asm("v_pk_min_f16 %0, %1, %2":"=v"(d):"v"(a),"v"(b));return d;}
__device__ __forceinline__ u32 pmax2(u32 a,u32 b){u32 d;asm("v_pk_max_f16 %0, %1, %2":"=v"(d):"v"(a),"v"(b));return d;}
__device__ __forceinline__ u32 shpair(u32 hiSrc,u32 loSrc){return __builtin_amdgcn_alignbit(hiSrc,loSrc,16);}
#define INF2P 0x7C007C00u
#define INF2N 0xFC00FC00u

// MODE 0: init erode — stage f16(input), write e1 = sigmoid(E(x)) (pred vols) / E(y) (true)
// MODE 1: fused first — ghalo=e1, aimg from fp32 input (sigmoided), skel init; write e2
// MODE 2: fused mid   — skel RMW; eaw read pointwise then overwritten with e_{t+2}
// MODE 3: fused last  — skel RMW only, no e write
template<int MODE>
__global__ __launch_bounds__(NT) void step_kernel(const u16* __restrict__ ghalo,
                                                  u16* __restrict__ eaw,
                                                  const float* __restrict__ ypred,
                                                  const float* __restrict__ ytrue,
                                                  u16* __restrict__ skel) {
    const int tx = threadIdx.x & 31;
    const int ty = threadIdx.x >> 5;
    const int x0 = blockIdx.x * TX;
    const int y0 = blockIdx.y * TY;
    const int vol = blockIdx.z / NSLAB;
    const int z0 = (blockIdx.z % NSLAB) * ZS;
    const size_t base = (size_t)vol * DHW;
    const int gxc = x0 + 4*tx;     // 4 px per lane, 8B/16B aligned accesses
    const int gyc = y0 + ty;

    const float* fin = nullptr;
    bool dosig = false;
    if (MODE == 0 || MODE == 1) {
        if (vol < 2) { fin = ypred + base; dosig = true; }
        else         { fin = ytrue + (size_t)(vol-2)*DHW; }
    }

    // packed-f16 raw plane: u32 pair w <-> px (x0-2+2w, x0-2+2w+1), rows gy=y0-1+r
    __shared__ u32 raw[2][TY+2][RPAIRS];

    auto stage = [&](int zi, int buf) {
        if ((unsigned)zi >= DDP) return;
        if (MODE == 0) {
            const float* pl = fin + (size_t)zi * HWP;
            for (int idx = threadIdx.x; idx < (TY+2)*RPAIRS; idx += NT) {
                int r = idx / RPAIRS;
                int w = idx - r*RPAIRS;
                const float* rp = pl + (size_t)icl(y0-1+r, HH-1) * WW;
                int gx0 = x0 - 2 + 2*w;
                float v0, v1;
                if (gx0 < 0)        { v0 = v1 = rp[0]; }
                else if (gx0 >= WW) { v0 = v1 = rp[WW-1]; }
                else { float2 fv = *(const float2*)(rp + gx0); v0 = fv.x; v1 = fv.y; }
                raw[buf][r][w] = dn2(v0, v1);
            }
        } else {
            const u16* pl = ghalo + base + (size_t)zi * HWP;
            for (int idx = threadIdx.x; idx < (TY+2)*RPAIRS; idx += NT) {
                int r = idx / RPAIRS;
                int w = idx - r*RPAIRS;
                const u16* rp = pl + (size_t)icl(y0-1+r, HH-1) * WW;
                int gx0 = x0 - 2 + 2*w;
                u32 v;
                if (gx0 < 0)        { u32 t = rp[0];    v = t | (t<<16); }
                else if (gx0 >= WW) { u32 t = rp[WW-1]; v = t | (t<<16); }
                else v = *(const u32*)(rp + gx0);
                raw[buf][r][w] = v;
            }
        }
    };

    const int wl = 2*tx;           // left staged col of this lane's 4-col window
    // z-rings for 2 output pairs (named regs, compile-time indexed)
    u32 n00,n01,n02, n10,n11,n12;  // erosion
    u32 m00,m01,m02, m10,m11,m12;  // dilation
    n00=n01=n02=n10=n11=n12=INF2P;
    m00=m01=m02=m10=m11=m12=INF2N;

    stage(z0-1, (z0-1)&1);
    __syncthreads();

    for (int zi = z0-1; zi <= z0+ZS; ++zi) {
        if (zi < z0+ZS) stage(zi+1, (zi+1)&1);    // issue next plane's loads early

        u32 xn0=INF2P, xn1=INF2P, xm0=INF2N, xm1=INF2N;
        if ((unsigned)zi < DDP) {
            const int b = zi & 1;
            u32 rn0=INF2P, rn1=INF2P, rm0=INF2N, rm1=INF2N;
            #pragma unroll
            for (int dr = 0; dr < 3; ++dr) {
                const u32* rp = &raw[b][ty+dr][wl];
                u32 L = rp[0], M0 = rp[1], M1 = rp[2], R = rp[3];
                u32 ls0 = shpair(M0, L), rs0 = shpair(M1, M0), rs1 = shpair(R, M1);
                rn0 = pmin2(rn0, pmin2(M0, pmin2(ls0, rs0)));
                rn1 = pmin2(rn1, pmin2(M1, pmin2(rs0, rs1)));
                if (MODE != 0) {
                    rm0 = pmax2(rm0, pmax2(M0, pmax2(ls0, rs0)));
                    rm1 = pmax2(rm1, pmax2(M1, pmax2(rs0, rs1)));
                }
            }
            xn0 = rn0; xn1 = rn1; xm0 = rm0; xm1 = rm1;
        }
        n00=n01; n01=n02; n02=xn0;  n10=n11; n11=n12; n12=xn1;
        if (MODE != 0) { m00=m01; m01=m02; m02=xm0;  m10=m11; m11=m12; m12=xm1; }

        if (zi >= z0+1) {
            const int zc = zi - 1;
            size_t voff = (size_t)zc*HWP + (size_t)gyc*WW + gxc;
            size_t idx = base + voff;
            u32 e0 = pmin2(n00, pmin2(n01, n02));
            u32 e1 = pmin2(n10, pmin2(n11, n12));
            if (MODE == 0) {
                if (dosig) {
                    float2 f0 = up2(e0), f1 = up2(e1);
                    e0 = dn2(sigm(f0.x), sigm(f0.y));
                    e1 = dn2(sigm(f1.x), sigm(f1.y));
                }
                *(uint2*)(eaw + idx) = make_uint2(e0, e1);
            } else {
                float2 mA = up2(pmax2(m00, pmax2(m01, m02)));
                float2 mB = up2(pmax2(m10, pmax2(m11, m12)));
                float av0, av1, av2, av3;
                if (MODE == 1) {
                    float4 fv = *(const float4*)(fin + voff);
                    av0=fv.x; av1=fv.y; av2=fv.z; av3=fv.w;
                    if (dosig) { av0=sigm(av0); av1=sigm(av1); av2=sigm(av2); av3=sigm(av3); }
                } else {
                    uint2 c2 = *(const uint2*)(eaw + idx);
                    float2 c0 = up2(c2.x), c1 = up2(c2.y);
                    av0=c0.x; av1=c0.y; av2=c1.x; av3=c1.y;
                }
                float d0 = fmaxf(av0 - mA.x, 0.f);
                float d1 = fmaxf(av1 - mA.y, 0.f);
                float d2 = fmaxf(av2 - mB.x, 0.f);
                float d3 = fmaxf(av3 - mB.y, 0.f);
                uint2 pk;
                if (MODE == 1) {
                    pk = make_uint2(dn2(d0, d1), dn2(d2, d3));
                } else {
                    uint2 sv = *(const uint2*)(skel + idx);
                    float2 s0 = up2(sv.x), s1 = up2(sv.y);
                    s0.x += fmaxf(d0 - s0.x*d0, 0.f);
                    s0.y += fmaxf(d1 - s0.y*d1, 0.f);
                    s1.x += fmaxf(d2 - s1.x*d2, 0.f);
                    s1.y += fmaxf(d3 - s1.y*d3, 0.f);
                    pk = make_uint2(dn2(s0.x, s0.y), dn2(s1.x, s1.y));
                }
                *(uint2*)(skel + idx) = pk;
                if (MODE != 3) *(uint2*)(eaw + idx) = make_uint2(e0, e1);
            }
        }
        __syncthreads();
    }
}

// ---------------- deterministic 4-sum reduction (vols 0,1 = pred; 2,3 = true) ----------------
__global__ __launch_bounds__(256) void reduce4_kernel(const u16* __restrict__ skel,
                                                      const float* __restrict__ ytrue,
                                                      const float* __restrict__ ypred,
                                                      float* __restrict__ part) {
    const u32* sp = (const u32*)skel;
    const u32* st = (const u32*)(skel + N2);
    const float2* yt = (const float2*)ytrue;
    const float2* yp = (const float2*)ypred;
    float a0=0.f,a1=0.f,a2=0.f,a3=0.f;
    for (int i = blockIdx.x*256 + threadIdx.x; i < N2/2; i += gridDim.x*256) {
        float2 s = up2(sp[i]);
        float2 u = up2(st[i]);
        float2 t = yt[i]; float2 q = yp[i];
        a0 += s.x*t.x + s.y*t.y;
        a1 += s.x + s.y;
        a2 += u.x*sigm(q.x) + u.y*sigm(q.y);
        a3 += u.x + u.y;
    }
    for (int off=32; off>0; off>>=1) {
        a0+=__shfl_down(a0,off); a1+=__shfl_down(a1,off);
        a2+=__shfl_down(a2,off); a3+=__shfl_down(a3,off);
    }
    __shared__ float red[4][4];
    int wave = threadIdx.x>>6;
    if ((threadIdx.x&63)==0){red[wave][0]=a0;red[wave][1]=a1;red[wave][2]=a2;red[wave][3]=a3;}
    __syncthreads();
    if (threadIdx.x==0){
        float s0=0,s1=0,s2=0,s3=0;
        for(int w=0;w<4;++w){s0+=red[w][0];s1+=red[w][1];s2+=red[w][2];s3+=red[w][3];}
        part[0*RED_BLOCKS+blockIdx.x]=s0; part[1*RED_BLOCKS+blockIdx.x]=s1;
        part[2*RED_BLOCKS+blockIdx.x]=s2; part[3*RED_BLOCKS+blockIdx.x]=s3;
    }
}

__global__ __launch_bounds__(256) void finalize_kernel(const float* __restrict__ part,
                                                       float* __restrict__ out) {
    float a0=0.f,a1=0.f,a2=0.f,a3=0.f;
    for (int i=threadIdx.x;i<RED_BLOCKS;i+=256){
        a0+=part[0*RED_BLOCKS+i]; a1+=part[1*RED_BLOCKS+i];
        a2+=part[2*RED_BLOCKS+i]; a3+=part[3*RED_BLOCKS+i];
    }
    for (int off=32; off>0; off>>=1){
        a0+=__shfl_down(a0,off); a1+=__shfl_down(a1,off);
        a2+=__shfl_down(a2,off); a3+=__shfl_down(a3,off);
    }
    __shared__ float red[4][4];
    int wave = threadIdx.x>>6;
    if ((threadIdx.x&63)==0){red[wave][0]=a0;red[wave][1]=a1;red[wave][2]=a2;red[wave][3]=a3;}
    __syncthreads();
    if (threadIdx.x==0){
        float s0=0,s1=0,s2=0,s3=0;
        for(int w=0;w<4;++w){s0+=red[w][0];s1+=red[w][1];s2+=red[w][2];s3+=red[w][3];}
        float tprec=(s0+1.f)/(s1+1.f);
        float tsens=(s2+1.f)/(s3+1.f);
        float cl2=2.f*tprec*tsens/(tprec+tsens+1.f);
        out[0]=1.f-cl2;
    }
}

__global__ void sentinel_kernel(float* out, float v){ out[0]=v; }

extern "C" void kernel_launch(void* const* d_in, const int* in_sizes, int n_in,
                              void* d_out, int out_size, void* d_ws, size_t ws_size,
                              hipStream_t stream) {
    const float* ypred = (const float*)d_in[0];
    const float* ytrue = (const float*)d_in[1];
    float* out = (float*)d_out;

    const size_t need = (size_t)3*N4*sizeof(u16) + (size_t)4*RED_BLOCKS*sizeof(float);
    if (ws_size < need) { sentinel_kernel<<<1,1,0,stream>>>(out,-111111.f); return; }

    u16* EA   = (u16*)d_ws;
    u16* EB   = EA + N4;
    u16* SKEL = EB + N4;
    float* PART = (float*)(SKEL + N4);

    dim3 grid(WW/TX, HH/TY, 4*NSLAB);   // 2 x 32 x 32 = 2048 blocks = 8/CU, one round

    // EB = e_1 = E(f(x))   (sigmoid fused at write for pred vols)
    step_kernel<0><<<grid, NT, 0, stream>>>(nullptr, EB, ypred, ytrue, nullptr);
    // skel = relu(e_0 - M(e_1));  EA <- e_2 = E(e_1)
    step_kernel<1><<<grid, NT, 0, stream>>>(EB, EA, ypred, ytrue, SKEL);

    u16* h = EA;   // e_{t+1}
    u16* a = EB;   // e_t  (overwritten with e_{t+2})
    for (int t = 1; t <= NITER; ++t) {
        if (t < NITER) step_kernel<2><<<grid, NT, 0, stream>>>(h, a, nullptr, nullptr, SKEL);
        else           step_kernel<3><<<grid, NT, 0, stream>>>(h, a, nullptr, nullptr, SKEL);
        u16* tmp = h; h = a; a = tmp;
    }

    reduce4_kernel<<<RED_BLOCKS, 256, 0, stream>>>(SKEL, ytrue, ypred, PART);
    finalize_kernel<<<1, 256, 0, stream>>>(PART, out);
}

// Round 13
// 1943.885 us; speedup vs baseline: 1.2376x; 1.0690x over previous
//
#include <hip/hip_runtime.h>
#include <hip/hip_fp16.h>
#include <math.h>

#define WW 256
#define HH 256
#define DDP 96
#define HWP (WW*HH)
#define DHW (DDP*HWP)
#define N2 (2*DHW)
#define N4 (4*DHW)
#define TX 128                  // 32 lanes x 2 px-pairs (4 px) per lane
#define TY 8
#define NT 256
#define ZS 12
#define NSLAB (DDP/ZS)          // 8
#define RED_BLOCKS 1024
#define NITER 40
#define RPAIRS 66               // staged u32 pairs per row: px x0-2 .. x0+129
#define NSLOT ((TY+2)*RPAIRS)   // 660 staged pairs per plane

typedef unsigned int u32;
typedef unsigned short u16;
typedef __half2 h2;

__device__ __forceinline__ float sigm(float x){return 1.f/(1.f+expf(-x));}
__device__ __forceinline__ int   icl(int v,int hi){return min(max(v,0),hi);}
__device__ __forceinline__ u32 h2u(h2 v){return __builtin_bit_cast(u32,v);}
__device__ __forceinline__ h2  u2h(u32 v){return __builtin_bit_cast(h2,v);}
__device__ __forceinline__ float2 up2(u32 v){return __half22float2(u2h(v));}
__device__ __forceinline__ u32 dn2(float a,float b){return h2u(__floats2half2_rn(a,b));}
__device__ __forceinline__ u32 pmin2(u32 a,u32 b){u32 d;asm("v_pk_min_f16 %0, %1, %2":"=v"(d):"v"(a),"v"(b));return d;}
__device__ __forceinline__ u32 pmax2(u32 a,u32 b){u32 d;asm("v_pk_max_f16 %0, %1, %2":"=v"(d):"v"(a),"v"(b));return d;}
__device__ __forceinline__ u32 shpair(u32 hiSrc,u32 loSrc){return __builtin_amdgcn_alignbit(hiSrc,loSrc,16);}
// splat-fix: m==1 -> both halves = lo; m==2 -> both halves = hi
__device__ __forceinline__ u32 sfix(u32 v,int m){
    if (m == 1) v = (v & 0xffffu) | (v << 16);
    else if (m == 2) v = (v >> 16) | (v & 0xffff0000u);
    return v;
}
#define INF2P 0x7C007C00u
#define INF2N 0xFC00FC00u

// MODE 0: init erode — stage f16(input), write e1 = sigmoid(E(x)) (pred vols) / E(y) (true)
// MODE 1: fused first — ghalo=e1, aimg from fp32 input (sigmoided), skel init; write e2
// MODE 2: fused mid   — skel RMW; eaw read pointwise then overwritten with e_{t+2}
// MODE 3: fused last  — skel RMW only, no e write
template<int MODE>
__global__ __launch_bounds__(NT) void step_kernel(const u16* __restrict__ ghalo,
                                                  u16* __restrict__ eaw,
                                                  const float* __restrict__ ypred,
                                                  const float* __restrict__ ytrue,
                                                  u16* __restrict__ skel) {
    const int tx = threadIdx.x & 31;
    const int ty = threadIdx.x >> 5;
    const int x0 = blockIdx.x * TX;
    const int y0 = blockIdx.y * TY;
    const int vol = blockIdx.z / NSLAB;
    const int z0 = (blockIdx.z % NSLAB) * ZS;
    const size_t base = (size_t)vol * DHW;
    const int gxc = x0 + 4*tx;     // 4 px per lane
    const int gyc = y0 + ty;

    const float* fin = nullptr;
    bool dosig = false;
    if (MODE == 0 || MODE == 1) {
        if (vol < 2) { fin = ypred + base; dosig = true; }
        else         { fin = ytrue + (size_t)(vol-2)*DHW; }
    }

    __shared__ u32 raw[2][TY+2][RPAIRS];

    // ---- precompute 3 fixed staging slots (hoisted out of z-loop) ----
    // slot k handles linear index tid + k*NT; slots 0,1 always valid, slot 2 iff tid < NSLOT-2*NT.
    const bool s2v = threadIdx.x < (NSLOT - 2*NT);
    u32 lo0, lo1, lo2;          // LDS u32 offsets within one buf
    int md0, md1, md2;          // splat modes
    size_t po0, po1, po2;       // within-plane element offsets (clamped)
    {
        #define SLOTSETUP(K, LO, MD, PO) {                         \
            int idx = threadIdx.x + (K)*NT;                        \
            int r = idx / RPAIRS;                                  \
            int w = idx - r*RPAIRS;                                \
            int gy = icl(y0-1+r, HH-1);                            \
            int gx0 = x0 - 2 + 2*w;                                \
            int m = 0, gx = gx0;                                   \
            if (gx0 < 0) { m = 1; gx = 0; }                        \
            else if (gx0 >= WW) { m = 2; gx = WW-2; }              \
            LO = r*RPAIRS + w; MD = m;                             \
            PO = (size_t)gy*WW + gx; }
        SLOTSETUP(0, lo0, md0, po0)
        SLOTSETUP(1, lo1, md1, po1)
        if (s2v) { SLOTSETUP(2, lo2, md2, po2) } else { lo2 = 0; md2 = 0; po2 = 0; }
        #undef SLOTSETUP
    }
    // running global pointers at plane z0-1
    const u16*   hp0 = nullptr; const u16* hp1 = nullptr; const u16* hp2 = nullptr;
    const float* fp0 = nullptr; const float* fp1 = nullptr; const float* fp2 = nullptr;
    if (MODE == 0) {
        fp0 = fin + po0 + (size_t)(z0-1)*HWP;
        fp1 = fin + po1 + (size_t)(z0-1)*HWP;
        fp2 = fin + po2 + (size_t)(z0-1)*HWP;
    } else {
        hp0 = ghalo + base + po0 + (size_t)(z0-1)*HWP;
        hp1 = ghalo + base + po1 + (size_t)(z0-1)*HWP;
        hp2 = ghalo + base + po2 + (size_t)(z0-1)*HWP;
    }

    // prologue: stage plane z0-1 into buf (z0-1)&1
    if (z0 >= 1) {
        const int b = (z0-1) & 1;
        u32 v0, v1, v2 = 0;
        if (MODE == 0) {
            float2 f0 = *(const float2*)fp0; v0 = dn2(f0.x, f0.y);
            float2 f1 = *(const float2*)fp1; v1 = dn2(f1.x, f1.y);
            if (s2v) { float2 f2 = *(const float2*)fp2; v2 = dn2(f2.x, f2.y); }
        } else {
            v0 = *(const u32*)hp0;
            v1 = *(const u32*)hp1;
            if (s2v) v2 = *(const u32*)hp2;
        }
        (&raw[b][0][0])[lo0] = sfix(v0, md0);
        (&raw[b][0][0])[lo1] = sfix(v1, md1);
        if (s2v) (&raw[b][0][0])[lo2] = sfix(v2, md2);
    }
    __syncthreads();

    const int wl = 2*tx;           // left staged col of this lane's 4-col window
    u32 n00,n01,n02, n10,n11,n12;  // erosion z-rings (2 output pairs)
    u32 m00,m01,m02, m10,m11,m12;  // dilation z-rings
    n00=n01=n02=n10=n11=n12=INF2P;
    m00=m01=m02=m10=m11=m12=INF2N;

    for (int zi = z0-1; zi <= z0+ZS; ++zi) {
        // advance running pointers to plane zi+1
        if (MODE == 0) { fp0 += HWP; fp1 += HWP; fp2 += HWP; }
        else           { hp0 += HWP; hp1 += HWP; hp2 += HWP; }
        const bool stage_ok = (zi < z0+ZS) && ((unsigned)(zi+1) < DDP);

        // T14: issue next plane's global loads FIRST (into regs)
        u32 v0 = 0, v1 = 0, v2 = 0;
        if (stage_ok) {
            if (MODE == 0) {
                float2 f0 = *(const float2*)fp0; v0 = dn2(f0.x, f0.y);
                float2 f1 = *(const float2*)fp1; v1 = dn2(f1.x, f1.y);
                if (s2v) { float2 f2 = *(const float2*)fp2; v2 = dn2(f2.x, f2.y); }
            } else {
                v0 = *(const u32*)hp0;
                v1 = *(const u32*)hp1;
                if (s2v) v2 = *(const u32*)hp2;
            }
        }

        // compute 3x3 xy window (packed) from buf zi&1
        u32 xn0=INF2P, xn1=INF2P, xm0=INF2N, xm1=INF2N;
        if ((unsigned)zi < DDP) {
            const int b = zi & 1;
            u32 rn0=INF2P, rn1=INF2P, rm0=INF2N, rm1=INF2N;
            #pragma unroll
            for (int dr = 0; dr < 3; ++dr) {
                uint2 pA = *(const uint2*)&raw[b][ty+dr][wl];
                uint2 pB = *(const uint2*)&raw[b][ty+dr][wl+2];
                u32 L = pA.x, M0 = pA.y, M1 = pB.x, R = pB.y;
                u32 ls0 = shpair(M0, L), rs0 = shpair(M1, M0), rs1 = shpair(R, M1);
                rn0 = pmin2(rn0, pmin2(M0, pmin2(ls0, rs0)));
                rn1 = pmin2(rn1, pmin2(M1, pmin2(rs0, rs1)));
                if (MODE != 0) {
                    rm0 = pmax2(rm0, pmax2(M0, pmax2(ls0, rs0)));
                    rm1 = pmax2(rm1, pmax2(M1, pmax2(rs0, rs1)));
                }
            }
            xn0 = rn0; xn1 = rn1; xm0 = rm0; xm1 = rm1;
        }
        n00=n01; n01=n02; n02=xn0;  n10=n11; n11=n12; n12=xn1;
        if (MODE != 0) { m00=m01; m01=m02; m02=xm0;  m10=m11; m11=m12; m12=xm1; }

        // output plane zc = zi-1
        if (zi >= z0+1) {
            const int zc = zi - 1;
            size_t voff = (size_t)zc*HWP + (size_t)gyc*WW + gxc;
            size_t idx = base + voff;
            u32 e0 = pmin2(n00, pmin2(n01, n02));
            u32 e1 = pmin2(n10, pmin2(n11, n12));
            if (MODE == 0) {
                if (dosig) {
                    float2 f0 = up2(e0), f1 = up2(e1);
                    e0 = dn2(sigm(f0.x), sigm(f0.y));
                    e1 = dn2(sigm(f1.x), sigm(f1.y));
                }
                *(uint2*)(eaw + idx) = make_uint2(e0, e1);
            } else {
                float2 mA = up2(pmax2(m00, pmax2(m01, m02)));
                float2 mB = up2(pmax2(m10, pmax2(m11, m12)));
                float av0, av1, av2, av3;
                if (MODE == 1) {
                    float4 fv = *(const float4*)(fin + voff);
                    av0=fv.x; av1=fv.y; av2=fv.z; av3=fv.w;
                    if (dosig) { av0=sigm(av0); av1=sigm(av1); av2=sigm(av2); av3=sigm(av3); }
                } else {
                    uint2 c2 = *(const uint2*)(eaw + idx);
                    float2 c0 = up2(c2.x), c1 = up2(c2.y);
                    av0=c0.x; av1=c0.y; av2=c1.x; av3=c1.y;
                }
                float d0 = fmaxf(av0 - mA.x, 0.f);
                float d1 = fmaxf(av1 - mA.y, 0.f);
                float d2 = fmaxf(av2 - mB.x, 0.f);
                float d3 = fmaxf(av3 - mB.y, 0.f);
                uint2 pk;
                if (MODE == 1) {
                    pk = make_uint2(dn2(d0, d1), dn2(d2, d3));
                } else {
                    uint2 sv = *(const uint2*)(skel + idx);
                    float2 s0 = up2(sv.x), s1 = up2(sv.y);
                    s0.x += fmaxf(d0 - s0.x*d0, 0.f);
                    s0.y += fmaxf(d1 - s0.y*d1, 0.f);
                    s1.x += fmaxf(d2 - s1.x*d2, 0.f);
                    s1.y += fmaxf(d3 - s1.y*d3, 0.f);
                    pk = make_uint2(dn2(s0.x, s0.y), dn2(s1.x, s1.y));
                }
                *(uint2*)(skel + idx) = pk;
                if (MODE != 3) *(uint2*)(eaw + idx) = make_uint2(e0, e1);
            }
        }

        // T14 tail: splat-fix + LDS write of the prefetched plane, then barrier
        if (stage_ok) {
            const int b = (zi+1) & 1;
            (&raw[b][0][0])[lo0] = sfix(v0, md0);
            (&raw[b][0][0])[lo1] = sfix(v1, md1);
            if (s2v) (&raw[b][0][0])[lo2] = sfix(v2, md2);
        }
        __syncthreads();
    }
}

// ---------------- deterministic 4-sum reduction (vols 0,1 = pred; 2,3 = true) ----------------
__global__ __launch_bounds__(256) void reduce4_kernel(const u16* __restrict__ skel,
                                                      const float* __restrict__ ytrue,
                                                      const float* __restrict__ ypred,
                                                      float* __restrict__ part) {
    const u32* sp = (const u32*)skel;
    const u32* st = (const u32*)(skel + N2);
    const float2* yt = (const float2*)ytrue;
    const float2* yp = (const float2*)ypred;
    float a0=0.f,a1=0.f,a2=0.f,a3=0.f;
    for (int i = blockIdx.x*256 + threadIdx.x; i < N2/2; i += gridDim.x*256) {
        float2 s = up2(sp[i]);
        float2 u = up2(st[i]);
        float2 t = yt[i]; float2 q = yp[i];
        a0 += s.x*t.x + s.y*t.y;
        a1 += s.x + s.y;
        a2 += u.x*sigm(q.x) + u.y*sigm(q.y);
        a3 += u.x + u.y;
    }
    for (int off=32; off>0; off>>=1) {
        a0+=__shfl_down(a0,off); a1+=__shfl_down(a1,off);
        a2+=__shfl_down(a2,off); a3+=__shfl_down(a3,off);
    }
    __shared__ float red[4][4];
    int wave = threadIdx.x>>6;
    if ((threadIdx.x&63)==0){red[wave][0]=a0;red[wave][1]=a1;red[wave][2]=a2;red[wave][3]=a3;}
    __syncthreads();
    if (threadIdx.x==0){
        float s0=0,s1=0,s2=0,s3=0;
        for(int w=0;w<4;++w){s0+=red[w][0];s1+=red[w][1];s2+=red[w][2];s3+=red[w][3];}
        part[0*RED_BLOCKS+blockIdx.x]=s0; part[1*RED_BLOCKS+blockIdx.x]=s1;
        part[2*RED_BLOCKS+blockIdx.x]=s2; part[3*RED_BLOCKS+blockIdx.x]=s3;
    }
}

__global__ __launch_bounds__(256) void finalize_kernel(const float* __restrict__ part,
                                                       float* __restrict__ out) {
    float a0=0.f,a1=0.f,a2=0.f,a3=0.f;
    for (int i=threadIdx.x;i<RED_BLOCKS;i+=256){
        a0+=part[0*RED_BLOCKS+i]; a1+=part[1*RED_BLOCKS+i];
        a2+=part[2*RED_BLOCKS+i]; a3+=part[3*RED_BLOCKS+i];
    }
    for (int off=32; off>0; off>>=1){
        a0+=__shfl_down(a0,off); a1+=__shfl_down(a1,off);
        a2+=__shfl_down(a2,off); a3+=__shfl_down(a3,off);
    }
    __shared__ float red[4][4];
    int wave = threadIdx.x>>6;
    if ((threadIdx.x&63)==0){red[wave][0]=a0;red[wave][1]=a1;red[wave][2]=a2;red[wave][3]=a3;}
    __syncthreads();
    if (threadIdx.x==0){
        float s0=0,s1=0,s2=0,s3=0;
        for(int w=0;w<4;++w){s0+=red[w][0];s1+=red[w][1];s2+=red[w][2];s3+=red[w][3];}
        float tprec=(s0+1.f)/(s1+1.f);
        float tsens=(s2+1.f)/(s3+1.f);
        float cl2=2.f*tprec*tsens/(tprec+tsens+1.f);
        out[0]=1.f-cl2;
    }
}

__global__ void sentinel_kernel(float* out, float v){ out[0]=v; }

extern "C" void kernel_launch(void* const* d_in, const int* in_sizes, int n_in,
                              void* d_out, int out_size, void* d_ws, size_t ws_size,
                              hipStream_t stream) {
    const float* ypred = (const float*)d_in[0];
    const float* ytrue = (const float*)d_in[1];
    float* out = (float*)d_out;

    const size_t need = (size_t)3*N4*sizeof(u16) + (size_t)4*RED_BLOCKS*sizeof(float);
    if (ws_size < need) { sentinel_kernel<<<1,1,0,stream>>>(out,-111111.f); return; }

    u16* EA   = (u16*)d_ws;
    u16* EB   = EA + N4;
    u16* SKEL = EB + N4;
    float* PART = (float*)(SKEL + N4);

    dim3 grid(WW/TX, HH/TY, 4*NSLAB);   // 2 x 32 x 32 = 2048 blocks = 8/CU

    // EB = e_1 = E(f(x))   (sigmoid fused at write for pred vols)
    step_kernel<0><<<grid, NT, 0, stream>>>(nullptr, EB, ypred, ytrue, nullptr);
    // skel = relu(e_0 - M(e_1));  EA <- e_2 = E(e_1)
    step_kernel<1><<<grid, NT, 0, stream>>>(EB, EA, ypred, ytrue, SKEL);

    u16* h = EA;   // e_{t+1}
    u16* a = EB;   // e_t  (overwritten with e_{t+2})
    for (int t = 1; t <= NITER; ++t) {
        if (t < NITER) step_kernel<2><<<grid, NT, 0, stream>>>(h, a, nullptr, nullptr, SKEL);
        else           step_kernel<3><<<grid, NT, 0, stream>>>(h, a, nullptr, nullptr, SKEL);
        u16* tmp = h; h = a; a = tmp;
    }

    reduce4_kernel<<<RED_BLOCKS, 256, 0, stream>>>(SKEL, ytrue, ypred, PART);
    finalize_kernel<<<1, 256, 0, stream>>>(PART, out);
}

// Round 14
// 1712.149 us; speedup vs baseline: 1.4051x; 1.1353x over previous
//
#include <hip/hip_runtime.h>
#include <hip/hip_fp16.h>
#include <math.h>

#define WW 256
#define HH 256
#define DDP 96
#define HWP (WW*HH)
#define DHW (DDP*HWP)
#define N2 (2*DHW)
#define N4 (4*DHW)
#define TX 128                  // 32 lanes x 2 px-pairs (4 px) per lane
#define TY 8
#define NT 256
#define ZS 12
#define NSLAB (DDP/ZS)          // 8
#define RED_BLOCKS 1024
#define NITER 40
#define RPAIRS 66               // staged u32 pairs per row: px x0-2 .. x0+129
#define NSLOT ((TY+2)*RPAIRS)   // 660 staged pairs per plane

typedef unsigned int u32;
typedef unsigned short u16;
typedef unsigned char u8;
typedef __half2 h2;

__device__ __forceinline__ float sigm(float x){return 1.f/(1.f+expf(-x));}
__device__ __forceinline__ int   icl(int v,int hi){return min(max(v,0),hi);}
__device__ __forceinline__ u32 h2u(h2 v){return __builtin_bit_cast(u32,v);}
__device__ __forceinline__ h2  u2h(u32 v){return __builtin_bit_cast(h2,v);}
__device__ __forceinline__ float2 up2(u32 v){return __half22float2(u2h(v));}
__device__ __forceinline__ u32 dn2(float a,float b){return h2u(__floats2half2_rn(a,b));}
__device__ __forceinline__ u32 pmin2(u32 a,u32 b){u32 d;asm("v_pk_min_f16 %0, %1, %2":"=v"(d):"v"(a),"v"(b));return d;}
__device__ __forceinline__ u32 pmax2(u32 a,u32 b){u32 d;asm("v_pk_max_f16 %0, %1, %2":"=v"(d):"v"(a),"v"(b));return d;}
__device__ __forceinline__ u32 shpair(u32 hiSrc,u32 loSrc){return __builtin_amdgcn_alignbit(hiSrc,loSrc,16);}
__device__ __forceinline__ u32 sfix(u32 v,int m){
    if (m == 1) v = (v & 0xffffu) | (v << 16);
    else if (m == 2) v = (v >> 16) | (v & 0xffff0000u);
    return v;
}
#define INF2P 0x7C007C00u
#define INF2N 0xFC00FC00u

// deterministic stochastic rounding: q_i = floor(s_i*255 + (th_i+0.5)/256), th_i = byte i of hash
__device__ __forceinline__ u32 pack_u8_sr(float s0,float s1,float s2,float s3,u32 h){
    float t0 = (float)( h        & 0xff);
    float t1 = (float)((h >>  8) & 0xff);
    float t2 = (float)((h >> 16) & 0xff);
    float t3 = (float)((h >> 24) & 0xff);
    int q0 = min((int)(s0*255.f + (t0+0.5f)*(1.f/256.f)), 255);
    int q1 = min((int)(s1*255.f + (t1+0.5f)*(1.f/256.f)), 255);
    int q2 = min((int)(s2*255.f + (t2+0.5f)*(1.f/256.f)), 255);
    int q3 = min((int)(s3*255.f + (t3+0.5f)*(1.f/256.f)), 255);
    return (u32)q0 | ((u32)q1<<8) | ((u32)q2<<16) | ((u32)q3<<24);
}

// MODE 0: init erode — stage f16(input), write e1 = sigmoid(E(x)) (pred vols) / E(y) (true)
// MODE 1: fused first — ghalo=e1, aimg from fp32 input (sigmoided), skel init (u8 SR); write e2
// MODE 2: fused mid   — skel u8 RMW; eaw read pointwise then overwritten with e_{t+2}
// MODE 3: fused last  — skel u8 RMW only, no e write
template<int MODE>
__global__ __launch_bounds__(NT) void step_kernel(const u16* __restrict__ ghalo,
                                                  u16* __restrict__ eaw,
                                                  const float* __restrict__ ypred,
                                                  const float* __restrict__ ytrue,
                                                  u8* __restrict__ skel,
                                                  int itno) {
    const int tx = threadIdx.x & 31;
    const int ty = threadIdx.x >> 5;
    const int x0 = blockIdx.x * TX;
    const int y0 = blockIdx.y * TY;
    const int vol = blockIdx.z / NSLAB;
    const int z0 = (blockIdx.z % NSLAB) * ZS;
    const size_t base = (size_t)vol * DHW;
    const int gxc = x0 + 4*tx;     // 4 px per lane
    const int gyc = y0 + ty;

    const float* fin = nullptr;
    bool dosig = false;
    if (MODE == 0 || MODE == 1) {
        if (vol < 2) { fin = ypred + base; dosig = true; }
        else         { fin = ytrue + (size_t)(vol-2)*DHW; }
    }

    __shared__ u32 raw[2][TY+2][RPAIRS];

    // ---- precompute 3 fixed staging slots (hoisted out of z-loop) ----
    const bool s2v = threadIdx.x < (NSLOT - 2*NT);
    u32 lo0, lo1, lo2;
    int md0, md1, md2;
    size_t po0, po1, po2;
    {
        #define SLOTSETUP(K, LO, MD, PO) {                         \
            int idx = threadIdx.x + (K)*NT;                        \
            int r = idx / RPAIRS;                                  \
            int w = idx - r*RPAIRS;                                \
            int gy = icl(y0-1+r, HH-1);                            \
            int gx0 = x0 - 2 + 2*w;                                \
            int m = 0, gx = gx0;                                   \
            if (gx0 < 0) { m = 1; gx = 0; }                        \
            else if (gx0 >= WW) { m = 2; gx = WW-2; }              \
            LO = r*RPAIRS + w; MD = m;                             \
            PO = (size_t)gy*WW + gx; }
        SLOTSETUP(0, lo0, md0, po0)
        SLOTSETUP(1, lo1, md1, po1)
        if (s2v) { SLOTSETUP(2, lo2, md2, po2) } else { lo2 = 0; md2 = 0; po2 = 0; }
        #undef SLOTSETUP
    }
    const u16*   hp0 = nullptr; const u16* hp1 = nullptr; const u16* hp2 = nullptr;
    const float* fp0 = nullptr; const float* fp1 = nullptr; const float* fp2 = nullptr;
    if (MODE == 0) {
        fp0 = fin + po0 + (size_t)(z0-1)*HWP;
        fp1 = fin + po1 + (size_t)(z0-1)*HWP;
        fp2 = fin + po2 + (size_t)(z0-1)*HWP;
    } else {
        hp0 = ghalo + base + po0 + (size_t)(z0-1)*HWP;
        hp1 = ghalo + base + po1 + (size_t)(z0-1)*HWP;
        hp2 = ghalo + base + po2 + (size_t)(z0-1)*HWP;
    }

    if (z0 >= 1) {
        const int b = (z0-1) & 1;
        u32 v0, v1, v2 = 0;
        if (MODE == 0) {
            float2 f0 = *(const float2*)fp0; v0 = dn2(f0.x, f0.y);
            float2 f1 = *(const float2*)fp1; v1 = dn2(f1.x, f1.y);
            if (s2v) { float2 f2 = *(const float2*)fp2; v2 = dn2(f2.x, f2.y); }
        } else {
            v0 = *(const u32*)hp0;
            v1 = *(const u32*)hp1;
            if (s2v) v2 = *(const u32*)hp2;
        }
        (&raw[b][0][0])[lo0] = sfix(v0, md0);
        (&raw[b][0][0])[lo1] = sfix(v1, md1);
        if (s2v) (&raw[b][0][0])[lo2] = sfix(v2, md2);
    }
    __syncthreads();

    const int wl = 2*tx;
    u32 n00,n01,n02, n10,n11,n12;
    u32 m00,m01,m02, m10,m11,m12;
    n00=n01=n02=n10=n11=n12=INF2P;
    m00=m01=m02=m10=m11=m12=INF2N;

    for (int zi = z0-1; zi <= z0+ZS; ++zi) {
        if (MODE == 0) { fp0 += HWP; fp1 += HWP; fp2 += HWP; }
        else           { hp0 += HWP; hp1 += HWP; hp2 += HWP; }
        const bool stage_ok = (zi < z0+ZS) && ((unsigned)(zi+1) < DDP);

        // T14: issue next plane's global loads FIRST (into regs)
        u32 v0 = 0, v1 = 0, v2 = 0;
        if (stage_ok) {
            if (MODE == 0) {
                float2 f0 = *(const float2*)fp0; v0 = dn2(f0.x, f0.y);
                float2 f1 = *(const float2*)fp1; v1 = dn2(f1.x, f1.y);
                if (s2v) { float2 f2 = *(const float2*)fp2; v2 = dn2(f2.x, f2.y); }
            } else {
                v0 = *(const u32*)hp0;
                v1 = *(const u32*)hp1;
                if (s2v) v2 = *(const u32*)hp2;
            }
        }

        u32 xn0=INF2P, xn1=INF2P, xm0=INF2N, xm1=INF2N;
        if ((unsigned)zi < DDP) {
            const int b = zi & 1;
            u32 rn0=INF2P, rn1=INF2P, rm0=INF2N, rm1=INF2N;
            #pragma unroll
            for (int dr = 0; dr < 3; ++dr) {
                uint2 pA = *(const uint2*)&raw[b][ty+dr][wl];
                uint2 pB = *(const uint2*)&raw[b][ty+dr][wl+2];
                u32 L = pA.x, M0 = pA.y, M1 = pB.x, R = pB.y;
                u32 ls0 = shpair(M0, L), rs0 = shpair(M1, M0), rs1 = shpair(R, M1);
                rn0 = pmin2(rn0, pmin2(M0, pmin2(ls0, rs0)));
                rn1 = pmin2(rn1, pmin2(M1, pmin2(rs0, rs1)));
                if (MODE != 0) {
                    rm0 = pmax2(rm0, pmax2(M0, pmax2(ls0, rs0)));
                    rm1 = pmax2(rm1, pmax2(M1, pmax2(rs0, rs1)));
                }
            }
            xn0 = rn0; xn1 = rn1; xm0 = rm0; xm1 = rm1;
        }
        n00=n01; n01=n02; n02=xn0;  n10=n11; n11=n12; n12=xn1;
        if (MODE != 0) { m00=m01; m01=m02; m02=xm0;  m10=m11; m11=m12; m12=xm1; }

        if (zi >= z0+1) {
            const int zc = zi - 1;
            size_t voff = (size_t)zc*HWP + (size_t)gyc*WW + gxc;
            size_t idx = base + voff;
            u32 e0 = pmin2(n00, pmin2(n01, n02));
            u32 e1 = pmin2(n10, pmin2(n11, n12));
            if (MODE == 0) {
                if (dosig) {
                    float2 f0 = up2(e0), f1 = up2(e1);
                    e0 = dn2(sigm(f0.x), sigm(f0.y));
                    e1 = dn2(sigm(f1.x), sigm(f1.y));
                }
                *(uint2*)(eaw + idx) = make_uint2(e0, e1);
            } else {
                float2 mA = up2(pmax2(m00, pmax2(m01, m02)));
                float2 mB = up2(pmax2(m10, pmax2(m11, m12)));
                float av0, av1, av2, av3;
                if (MODE == 1) {
                    float4 fv = *(const float4*)(fin + voff);
                    av0=fv.x; av1=fv.y; av2=fv.z; av3=fv.w;
                    if (dosig) { av0=sigm(av0); av1=sigm(av1); av2=sigm(av2); av3=sigm(av3); }
                } else {
                    uint2 c2 = *(const uint2*)(eaw + idx);
                    float2 c0 = up2(c2.x), c1 = up2(c2.y);
                    av0=c0.x; av1=c0.y; av2=c1.x; av3=c1.y;
                }
                float d0 = fmaxf(av0 - mA.x, 0.f);
                float d1 = fmaxf(av1 - mA.y, 0.f);
                float d2 = fmaxf(av2 - mB.x, 0.f);
                float d3 = fmaxf(av3 - mB.y, 0.f);
                // u8 skel RMW with deterministic stochastic rounding
                u32 lin = (u32)(idx >> 2);
                u32 h = lin * 2654435761u + (u32)itno * 0x9E3779B9u;
                u32* sp32 = (u32*)(skel + idx);
                u32 pk;
                if (MODE == 1) {
                    pk = pack_u8_sr(d0, d1, d2, d3, h);
                } else {
                    u32 sv = *sp32;
                    float s0 = (float)( sv        & 0xff) * (1.f/255.f);
                    float s1 = (float)((sv >>  8) & 0xff) * (1.f/255.f);
                    float s2 = (float)((sv >> 16) & 0xff) * (1.f/255.f);
                    float s3 = (float)((sv >> 24) & 0xff) * (1.f/255.f);
                    s0 += fmaxf(d0 - s0*d0, 0.f);
                    s1 += fmaxf(d1 - s1*d1, 0.f);
                    s2 += fmaxf(d2 - s2*d2, 0.f);
                    s3 += fmaxf(d3 - s3*d3, 0.f);
                    pk = pack_u8_sr(s0, s1, s2, s3, h);
                }
                *sp32 = pk;
                if (MODE != 3) *(uint2*)(eaw + idx) = make_uint2(e0, e1);
            }
        }

        if (stage_ok) {
            const int b = (zi+1) & 1;
            (&raw[b][0][0])[lo0] = sfix(v0, md0);
            (&raw[b][0][0])[lo1] = sfix(v1, md1);
            if (s2v) (&raw[b][0][0])[lo2] = sfix(v2, md2);
        }
        __syncthreads();
    }
}

// ---------------- deterministic 4-sum reduction (vols 0,1 = pred; 2,3 = true) ----------------
__global__ __launch_bounds__(256) void reduce4_kernel(const u8* __restrict__ skel,
                                                      const float* __restrict__ ytrue,
                                                      const float* __restrict__ ypred,
                                                      float* __restrict__ part) {
    const u32* sp = (const u32*)skel;            // pred vols, 4 px per u32
    const u32* st = (const u32*)(skel + N2);
    const float4* yt = (const float4*)ytrue;
    const float4* yp = (const float4*)ypred;
    float a0=0.f,a1=0.f,a2=0.f,a3=0.f;
    for (int i = blockIdx.x*256 + threadIdx.x; i < N2/4; i += gridDim.x*256) {
        u32 a = sp[i]; u32 b = st[i];
        float4 t = yt[i]; float4 q = yp[i];
        float s0 = (float)( a        & 0xff) * (1.f/255.f);
        float s1 = (float)((a >>  8) & 0xff) * (1.f/255.f);
        float s2 = (float)((a >> 16) & 0xff) * (1.f/255.f);
        float s3 = (float)((a >> 24) & 0xff) * (1.f/255.f);
        float u0 = (float)( b        & 0xff) * (1.f/255.f);
        float u1 = (float)((b >>  8) & 0xff) * (1.f/255.f);
        float u2v= (float)((b >> 16) & 0xff) * (1.f/255.f);
        float u3 = (float)((b >> 24) & 0xff) * (1.f/255.f);
        a0 += s0*t.x + s1*t.y + s2*t.z + s3*t.w;
        a1 += s0 + s1 + s2 + s3;
        a2 += u0*sigm(q.x) + u1*sigm(q.y) + u2v*sigm(q.z) + u3*sigm(q.w);
        a3 += u0 + u1 + u2v + u3;
    }
    for (int off=32; off>0; off>>=1) {
        a0+=__shfl_down(a0,off); a1+=__shfl_down(a1,off);
        a2+=__shfl_down(a2,off); a3+=__shfl_down(a3,off);
    }
    __shared__ float red[4][4];
    int wave = threadIdx.x>>6;
    if ((threadIdx.x&63)==0){red[wave][0]=a0;red[wave][1]=a1;red[wave][2]=a2;red[wave][3]=a3;}
    __syncthreads();
    if (threadIdx.x==0){
        float s0=0,s1=0,s2=0,s3=0;
        for(int w=0;w<4;++w){s0+=red[w][0];s1+=red[w][1];s2+=red[w][2];s3+=red[w][3];}
        part[0*RED_BLOCKS+blockIdx.x]=s0; part[1*RED_BLOCKS+blockIdx.x]=s1;
        part[2*RED_BLOCKS+blockIdx.x]=s2; part[3*RED_BLOCKS+blockIdx.x]=s3;
    }
}

__global__ __launch_bounds__(256) void finalize_kernel(const float* __restrict__ part,
                                                       float* __restrict__ out) {
    float a0=0.f,a1=0.f,a2=0.f,a3=0.f;
    for (int i=threadIdx.x;i<RED_BLOCKS;i+=256){
        a0+=part[0*RED_BLOCKS+i]; a1+=part[1*RED_BLOCKS+i];
        a2+=part[2*RED_BLOCKS+i]; a3+=part[3*RED_BLOCKS+i];
    }
    for (int off=32; off>0; off>>=1){
        a0+=__shfl_down(a0,off); a1+=__shfl_down(a1,off);
        a2+=__shfl_down(a2,off); a3+=__shfl_down(a3,off);
    }
    __shared__ float red[4][4];
    int wave = threadIdx.x>>6;
    if ((threadIdx.x&63)==0){red[wave][0]=a0;red[wave][1]=a1;red[wave][2]=a2;red[wave][3]=a3;}
    __syncthreads();
    if (threadIdx.x==0){
        float s0=0,s1=0,s2=0,s3=0;
        for(int w=0;w<4;++w){s0+=red[w][0];s1+=red[w][1];s2+=red[w][2];s3+=red[w][3];}
        float tprec=(s0+1.f)/(s1+1.f);
        float tsens=(s2+1.f)/(s3+1.f);
        float cl2=2.f*tprec*tsens/(tprec+tsens+1.f);
        out[0]=1.f-cl2;
    }
}

__global__ void sentinel_kernel(float* out, float v){ out[0]=v; }

extern "C" void kernel_launch(void* const* d_in, const int* in_sizes, int n_in,
                              void* d_out, int out_size, void* d_ws, size_t ws_size,
                              hipStream_t stream) {
    const float* ypred = (const float*)d_in[0];
    const float* ytrue = (const float*)d_in[1];
    float* out = (float*)d_out;

    // 2 x f16 e-buffers + u8 skel + partials = ~126 MB (under the proven 151 MB budget)
    const size_t need = (size_t)2*N4*sizeof(u16) + (size_t)N4 + (size_t)4*RED_BLOCKS*sizeof(float);
    if (ws_size < need) { sentinel_kernel<<<1,1,0,stream>>>(out,-111111.f); return; }

    u16* EA   = (u16*)d_ws;
    u16* EB   = EA + N4;
    u8*  SKEL = (u8*)(EB + N4);
    float* PART = (float*)(SKEL + N4);

    dim3 grid(WW/TX, HH/TY, 4*NSLAB);   // 2 x 32 x 32 = 2048 blocks = 8/CU

    // EB = e_1 = E(f(x))
    step_kernel<0><<<grid, NT, 0, stream>>>(nullptr, EB, ypred, ytrue, nullptr, 0);
    // skel = relu(e_0 - M(e_1)) (u8 SR);  EA <- e_2 = E(e_1)
    step_kernel<1><<<grid, NT, 0, stream>>>(EB, EA, ypred, ytrue, SKEL, 0);

    u16* h = EA;   // e_{t+1}
    u16* a = EB;   // e_t  (overwritten with e_{t+2})
    for (int t = 1; t <= NITER; ++t) {
        if (t < NITER) step_kernel<2><<<grid, NT, 0, stream>>>(h, a, nullptr, nullptr, SKEL, t);
        else           step_kernel<3><<<grid, NT, 0, stream>>>(h, a, nullptr, nullptr, SKEL, t);
        u16* tmp = h; h = a; a = tmp;
    }

    reduce4_kernel<<<RED_BLOCKS, 256, 0, stream>>>(SKEL, ytrue, ypred, PART);
    finalize_kernel<<<1, 256, 0, stream>>>(PART, out);
}

// Round 15
// 1668.843 us; speedup vs baseline: 1.4416x; 1.0259x over previous
//
#include <hip/hip_runtime.h>
#include <hip/hip_fp16.h>
#include <math.h>

#define WW 256
#define HH 256
#define DDP 96
#define HWP (WW*HH)
#define DHW (DDP*HWP)
#define N2 (2*DHW)
#define N4 (4*DHW)
#define TX 128                  // 32 lanes x 2 px-pairs (4 px) per lane
#define TY 8
#define NT 256
#define ZS 12
#define NSLAB (DDP/ZS)          // 8
#define RED_BLOCKS 1024
#define NITER 40
#define RPAIRS 66               // staged u32 pairs per row: px x0-2 .. x0+129
#define NSLOT ((TY+2)*RPAIRS)   // 660 staged pairs per plane

typedef unsigned int u32;
typedef unsigned short u16;
typedef unsigned char u8;
typedef __half2 h2;

__device__ __forceinline__ float sigm(float x){return 1.f/(1.f+expf(-x));}
__device__ __forceinline__ int   icl(int v,int hi){return min(max(v,0),hi);}
__device__ __forceinline__ u32 h2u(h2 v){return __builtin_bit_cast(u32,v);}
__device__ __forceinline__ h2  u2h(u32 v){return __builtin_bit_cast(h2,v);}
__device__ __forceinline__ float2 up2(u32 v){return __half22float2(u2h(v));}
__device__ __forceinline__ u32 dn2(float a,float b){return h2u(__floats2half2_rn(a,b));}
__device__ __forceinline__ u32 pmin2(u32 a,u32 b){u32 d;asm("v_pk_min_f16 %0, %1, %2":"=v"(d):"v"(a),"v"(b));return d;}
__device__ __forceinline__ u32 pmax2(u32 a,u32 b){u32 d;asm("v_pk_max_f16 %0, %1, %2":"=v"(d):"v"(a),"v"(b));return d;}
__device__ __forceinline__ u32 psub2(u32 a,u32 b){u32 d;asm("v_pk_add_f16 %0, %1, %2 neg_lo:[0,1] neg_hi:[0,1]":"=v"(d):"v"(a),"v"(b));return d;}
__device__ __forceinline__ u32 pfma2(u32 a,u32 b,u32 c){u32 d;asm("v_pk_fma_f16 %0, %1, %2, %3":"=v"(d):"v"(a),"v"(b),"v"(c));return d;}
__device__ __forceinline__ u32 shpair(u32 hiSrc,u32 loSrc){return __builtin_amdgcn_alignbit(hiSrc,loSrc,16);}
__device__ __forceinline__ u32 sfix(u32 v,int m){
    if (m == 1) v = (v & 0xffffu) | (v << 16);
    else if (m == 2) v = (v >> 16) | (v & 0xffff0000u);
    return v;
}
// two f32 (each an exact small integer) -> packed f16 pair via RTZ (exact for ints <= 2048)
__device__ __forceinline__ u32 pkrtz(float a,float b){
    return __builtin_bit_cast(u32, __builtin_amdgcn_cvt_pkrtz(a,b));
}
#define INF2P 0x7C007C00u
#define INF2N 0xFC00FC00u
#define C255_2 0x5BF85BF8u      // f16x2 {255,255}

// deterministic stochastic rounding (f32 values in [0,1]) -> u8x4
__device__ __forceinline__ u32 pack_u8_sr(float s0,float s1,float s2,float s3,u32 h){
    float t0 = (float)( h        & 0xff);
    float t1 = (float)((h >>  8) & 0xff);
    float t2 = (float)((h >> 16) & 0xff);
    float t3 = (float)((h >> 24) & 0xff);
    int q0 = min((int)(s0*255.f + (t0+0.5f)*(1.f/256.f)), 255);
    int q1 = min((int)(s1*255.f + (t1+0.5f)*(1.f/256.f)), 255);
    int q2 = min((int)(s2*255.f + (t2+0.5f)*(1.f/256.f)), 255);
    int q3 = min((int)(s3*255.f + (t3+0.5f)*(1.f/256.f)), 255);
    return (u32)q0 | ((u32)q1<<8) | ((u32)q2<<16) | ((u32)q3<<24);
}

// MODE 0: init erode — stage f16(input), write e1 = sigmoid(E(x)) (pred vols) / E(y) (true)
// MODE 1: fused first — ghalo=e1, aimg from fp32 input (sigmoided), skel init (u8 SR); write e2
// MODE 2: fused mid   — skel u8 RMW (packed-f16 S-domain); eaw read then overwritten with e_{t+2}
// MODE 3: fused last  — skel u8 RMW only, no e write
template<int MODE>
__global__ __launch_bounds__(NT) void step_kernel(const u16* __restrict__ ghalo,
                                                  u16* __restrict__ eaw,
                                                  const float* __restrict__ ypred,
                                                  const float* __restrict__ ytrue,
                                                  u8* __restrict__ skel,
                                                  int itno) {
    const int tx = threadIdx.x & 31;
    const int ty = threadIdx.x >> 5;
    const int x0 = blockIdx.x * TX;
    const int y0 = blockIdx.y * TY;
    const int vol = blockIdx.z / NSLAB;
    const int z0 = (blockIdx.z % NSLAB) * ZS;
    const size_t base = (size_t)vol * DHW;
    const int gxc = x0 + 4*tx;     // 4 px per lane
    const int gyc = y0 + ty;
    const size_t co = (size_t)gyc*WW + gxc;   // within-plane center offset

    const float* fin = nullptr;
    bool dosig = false;
    if (MODE == 0 || MODE == 1) {
        if (vol < 2) { fin = ypred + base; dosig = true; }
        else         { fin = ytrue + (size_t)(vol-2)*DHW; }
    }

    __shared__ u32 raw[2][TY+2][RPAIRS];

    // ---- precompute 3 fixed staging slots (hoisted out of z-loop) ----
    const bool s2v = threadIdx.x < (NSLOT - 2*NT);
    u32 lo0, lo1, lo2;
    int md0, md1, md2;
    size_t po0, po1, po2;
    {
        #define SLOTSETUP(K, LO, MD, PO) {                         \
            int idx = threadIdx.x + (K)*NT;                        \
            int r = idx / RPAIRS;                                  \
            int w = idx - r*RPAIRS;                                \
            int gy = icl(y0-1+r, HH-1);                            \
            int gx0 = x0 - 2 + 2*w;                                \
            int m = 0, gx = gx0;                                   \
            if (gx0 < 0) { m = 1; gx = 0; }                        \
            else if (gx0 >= WW) { m = 2; gx = WW-2; }              \
            LO = r*RPAIRS + w; MD = m;                             \
            PO = (size_t)gy*WW + gx; }
        SLOTSETUP(0, lo0, md0, po0)
        SLOTSETUP(1, lo1, md1, po1)
        if (s2v) { SLOTSETUP(2, lo2, md2, po2) } else { lo2 = 0; md2 = 0; po2 = 0; }
        #undef SLOTSETUP
    }
    const u16*   hp0 = nullptr; const u16* hp1 = nullptr; const u16* hp2 = nullptr;
    const float* fp0 = nullptr; const float* fp1 = nullptr; const float* fp2 = nullptr;
    if (MODE == 0) {
        fp0 = fin + po0 + (size_t)(z0-1)*HWP;
        fp1 = fin + po1 + (size_t)(z0-1)*HWP;
        fp2 = fin + po2 + (size_t)(z0-1)*HWP;
    } else {
        hp0 = ghalo + base + po0 + (size_t)(z0-1)*HWP;
        hp1 = ghalo + base + po1 + (size_t)(z0-1)*HWP;
        hp2 = ghalo + base + po2 + (size_t)(z0-1)*HWP;
    }

    if (z0 >= 1) {
        const int b = (z0-1) & 1;
        u32 v0, v1, v2 = 0;
        if (MODE == 0) {
            float2 f0 = *(const float2*)fp0; v0 = dn2(f0.x, f0.y);
            float2 f1 = *(const float2*)fp1; v1 = dn2(f1.x, f1.y);
            if (s2v) { float2 f2 = *(const float2*)fp2; v2 = dn2(f2.x, f2.y); }
        } else {
            v0 = *(const u32*)hp0;
            v1 = *(const u32*)hp1;
            if (s2v) v2 = *(const u32*)hp2;
        }
        (&raw[b][0][0])[lo0] = sfix(v0, md0);
        (&raw[b][0][0])[lo1] = sfix(v1, md1);
        if (s2v) (&raw[b][0][0])[lo2] = sfix(v2, md2);
    }
    __syncthreads();

    const int wl = 2*tx;
    u32 n00,n01,n02, n10,n11,n12;
    u32 m00,m01,m02, m10,m11,m12;
    n00=n01=n02=n10=n11=n12=INF2P;
    m00=m01=m02=m10=m11=m12=INF2N;

    // prefetched center/skel (consumed one iteration later)
    uint2 cv_c = make_uint2(0,0), cv_n = make_uint2(0,0);
    u32 sv_c = 0, sv_n = 0;
    float4 fv_c = make_float4(0,0,0,0), fv_n = make_float4(0,0,0,0);

    for (int zi = z0-1; zi <= z0+ZS; ++zi) {
        if (MODE == 0) { fp0 += HWP; fp1 += HWP; fp2 += HWP; }
        else           { hp0 += HWP; hp1 += HWP; hp2 += HWP; }
        const bool stage_ok = (zi < z0+ZS) && ((unsigned)(zi+1) < DDP);

        // T14: issue next plane's halo loads FIRST (into regs)
        u32 v0 = 0, v1 = 0, v2 = 0;
        if (stage_ok) {
            if (MODE == 0) {
                float2 f0 = *(const float2*)fp0; v0 = dn2(f0.x, f0.y);
                float2 f1 = *(const float2*)fp1; v1 = dn2(f1.x, f1.y);
                if (s2v) { float2 f2 = *(const float2*)fp2; v2 = dn2(f2.x, f2.y); }
            } else {
                v0 = *(const u32*)hp0;
                v1 = *(const u32*)hp1;
                if (s2v) v2 = *(const u32*)hp2;
            }
        }
        // T14: prefetch center/skel for output plane zi (consumed next iter)
        if (MODE != 0 && zi >= z0 && zi < z0+ZS) {
            size_t pidx = base + (size_t)zi*HWP + co;
            if (MODE == 1) {
                fv_n = *(const float4*)(fin + (size_t)zi*HWP + co);
            } else {
                cv_n = *(const uint2*)(eaw + pidx);
                sv_n = *(const u32*)(skel + pidx);
            }
        }

        // separable 3x3 xy window (y-fold then x-fold), packed f16
        u32 xn0=INF2P, xn1=INF2P, xm0=INF2N, xm1=INF2N;
        if ((unsigned)zi < DDP) {
            const int b = zi & 1;
            uint2 a0 = *(const uint2*)&raw[b][ty  ][wl];
            uint2 b0 = *(const uint2*)&raw[b][ty  ][wl+2];
            uint2 a1 = *(const uint2*)&raw[b][ty+1][wl];
            uint2 b1 = *(const uint2*)&raw[b][ty+1][wl+2];
            uint2 a2 = *(const uint2*)&raw[b][ty+2][wl];
            uint2 b2 = *(const uint2*)&raw[b][ty+2][wl+2];
            u32 vnL  = pmin2(a0.x, pmin2(a1.x, a2.x));
            u32 vnM0 = pmin2(a0.y, pmin2(a1.y, a2.y));
            u32 vnM1 = pmin2(b0.x, pmin2(b1.x, b2.x));
            u32 vnR  = pmin2(b0.y, pmin2(b1.y, b2.y));
            u32 lsn  = shpair(vnM0, vnL);
            u32 rsn  = shpair(vnM1, vnM0);
            u32 rs1n = shpair(vnR,  vnM1);
            xn0 = pmin2(vnM0, pmin2(lsn, rsn));
            xn1 = pmin2(vnM1, pmin2(rsn, rs1n));
            if (MODE != 0) {
                u32 vmL  = pmax2(a0.x, pmax2(a1.x, a2.x));
                u32 vmM0 = pmax2(a0.y, pmax2(a1.y, a2.y));
                u32 vmM1 = pmax2(b0.x, pmax2(b1.x, b2.x));
                u32 vmR  = pmax2(b0.y, pmax2(b1.y, b2.y));
                u32 lsm  = shpair(vmM0, vmL);
                u32 rsm  = shpair(vmM1, vmM0);
                u32 rs1m = shpair(vmR,  vmM1);
                xm0 = pmax2(vmM0, pmax2(lsm, rsm));
                xm1 = pmax2(vmM1, pmax2(rsm, rs1m));
            }
        }
        n00=n01; n01=n02; n02=xn0;  n10=n11; n11=n12; n12=xn1;
        if (MODE != 0) { m00=m01; m01=m02; m02=xm0;  m10=m11; m11=m12; m12=xm1; }

        if (zi >= z0+1) {
            const int zc = zi - 1;
            size_t idx = base + (size_t)zc*HWP + co;
            u32 e0 = pmin2(n00, pmin2(n01, n02));
            u32 e1 = pmin2(n10, pmin2(n11, n12));
            if (MODE == 0) {
                if (dosig) {
                    float2 f0 = up2(e0), f1 = up2(e1);
                    e0 = dn2(sigm(f0.x), sigm(f0.y));
                    e1 = dn2(sigm(f1.x), sigm(f1.y));
                }
                *(uint2*)(eaw + idx) = make_uint2(e0, e1);
            } else if (MODE == 1) {
                float2 mA = up2(pmax2(m00, pmax2(m01, m02)));
                float2 mB = up2(pmax2(m10, pmax2(m11, m12)));
                float av0=fv_c.x, av1=fv_c.y, av2=fv_c.z, av3=fv_c.w;
                if (dosig) { av0=sigm(av0); av1=sigm(av1); av2=sigm(av2); av3=sigm(av3); }
                float d0 = fmaxf(av0 - mA.x, 0.f);
                float d1 = fmaxf(av1 - mA.y, 0.f);
                float d2 = fmaxf(av2 - mB.x, 0.f);
                float d3 = fmaxf(av3 - mB.y, 0.f);
                u32 lin = (u32)(idx >> 2);
                u32 h = lin * 2654435761u + (u32)itno * 0x9E3779B9u;
                *(u32*)(skel + idx) = pack_u8_sr(d0, d1, d2, d3, h);
                *(uint2*)(eaw + idx) = make_uint2(e0, e1);
            } else {
                // packed-f16 S-domain tail: S_new = S + d*(255-S), d = max(av - M3, 0)
                u32 M3p0 = pmax2(m00, pmax2(m01, m02));
                u32 M3p1 = pmax2(m10, pmax2(m11, m12));
                u32 d0p = pmax2(psub2(cv_c.x, M3p0), 0u);
                u32 d1p = pmax2(psub2(cv_c.y, M3p1), 0u);
                u32 Sp0 = pkrtz((float)( sv_c        & 0xff), (float)((sv_c >>  8) & 0xff));
                u32 Sp1 = pkrtz((float)((sv_c >> 16) & 0xff), (float)((sv_c >> 24) & 0xff));
                u32 Sn0 = pfma2(d0p, psub2(C255_2, Sp0), Sp0);
                u32 Sn1 = pfma2(d1p, psub2(C255_2, Sp1), Sp1);
                float2 f0 = up2(Sn0), f1 = up2(Sn1);
                u32 lin = (u32)(idx >> 2);
                u32 h = lin * 2654435761u + (u32)itno * 0x9E3779B9u;
                u32 q0 = (u32)(f0.x + ((float)( h        & 0xff) + 0.5f)*(1.f/256.f));
                u32 q1 = (u32)(f0.y + ((float)((h >>  8) & 0xff) + 0.5f)*(1.f/256.f));
                u32 q2 = (u32)(f1.x + ((float)((h >> 16) & 0xff) + 0.5f)*(1.f/256.f));
                u32 q3 = (u32)(f1.y + ((float)((h >> 24) & 0xff) + 0.5f)*(1.f/256.f));
                *(u32*)(skel + idx) = q0 | (q1<<8) | (q2<<16) | (q3<<24);
                if (MODE != 3) *(uint2*)(eaw + idx) = make_uint2(e0, e1);
            }
        }
        cv_c = cv_n; sv_c = sv_n; fv_c = fv_n;

        if (stage_ok) {
            const int b = (zi+1) & 1;
            (&raw[b][0][0])[lo0] = sfix(v0, md0);
            (&raw[b][0][0])[lo1] = sfix(v1, md1);
            if (s2v) (&raw[b][0][0])[lo2] = sfix(v2, md2);
        }
        __syncthreads();
    }
}

// ---------------- deterministic 4-sum reduction (vols 0,1 = pred; 2,3 = true) ----------------
__global__ __launch_bounds__(256) void reduce4_kernel(const u8* __restrict__ skel,
                                                      const float* __restrict__ ytrue,
                                                      const float* __restrict__ ypred,
                                                      float* __restrict__ part) {
    const u32* sp = (const u32*)skel;
    const u32* st = (const u32*)(skel + N2);
    const float4* yt = (const float4*)ytrue;
    const float4* yp = (const float4*)ypred;
    float a0=0.f,a1=0.f,a2=0.f,a3=0.f;
    for (int i = blockIdx.x*256 + threadIdx.x; i < N2/4; i += gridDim.x*256) {
        u32 a = sp[i]; u32 b = st[i];
        float4 t = yt[i]; float4 q = yp[i];
        float s0 = (float)( a        & 0xff) * (1.f/255.f);
        float s1 = (float)((a >>  8) & 0xff) * (1.f/255.f);
        float s2 = (float)((a >> 16) & 0xff) * (1.f/255.f);
        float s3 = (float)((a >> 24) & 0xff) * (1.f/255.f);
        float u0 = (float)( b        & 0xff) * (1.f/255.f);
        float u1 = (float)((b >>  8) & 0xff) * (1.f/255.f);
        float u2v= (float)((b >> 16) & 0xff) * (1.f/255.f);
        float u3 = (float)((b >> 24) & 0xff) * (1.f/255.f);
        a0 += s0*t.x + s1*t.y + s2*t.z + s3*t.w;
        a1 += s0 + s1 + s2 + s3;
        a2 += u0*sigm(q.x) + u1*sigm(q.y) + u2v*sigm(q.z) + u3*sigm(q.w);
        a3 += u0 + u1 + u2v + u3;
    }
    for (int off=32; off>0; off>>=1) {
        a0+=__shfl_down(a0,off); a1+=__shfl_down(a1,off);
        a2+=__shfl_down(a2,off); a3+=__shfl_down(a3,off);
    }
    __shared__ float red[4][4];
    int wave = threadIdx.x>>6;
    if ((threadIdx.x&63)==0){red[wave][0]=a0;red[wave][1]=a1;red[wave][2]=a2;red[wave][3]=a3;}
    __syncthreads();
    if (threadIdx.x==0){
        float s0=0,s1=0,s2=0,s3=0;
        for(int w=0;w<4;++w){s0+=red[w][0];s1+=red[w][1];s2+=red[w][2];s3+=red[w][3];}
        part[0*RED_BLOCKS+blockIdx.x]=s0; part[1*RED_BLOCKS+blockIdx.x]=s1;
        part[2*RED_BLOCKS+blockIdx.x]=s2; part[3*RED_BLOCKS+blockIdx.x]=s3;
    }
}

__global__ __launch_bounds__(256) void finalize_kernel(const float* __restrict__ part,
                                                       float* __restrict__ out) {
    float a0=0.f,a1=0.f,a2=0.f,a3=0.f;
    for (int i=threadIdx.x;i<RED_BLOCKS;i+=256){
        a0+=part[0*RED_BLOCKS+i]; a1+=part[1*RED_BLOCKS+i];
        a2+=part[2*RED_BLOCKS+i]; a3+=part[3*RED_BLOCKS+i];
    }
    for (int off=32; off>0; off>>=1){
        a0+=__shfl_down(a0,off); a1+=__shfl_down(a1,off);
        a2+=__shfl_down(a2,off); a3+=__shfl_down(a3,off);
    }
    __shared__ float red[4][4];
    int wave = threadIdx.x>>6;
    if ((threadIdx.x&63)==0){red[wave][0]=a0;red[wave][1]=a1;red[wave][2]=a2;red[wave][3]=a3;}
    __syncthreads();
    if (threadIdx.x==0){
        float s0=0,s1=0,s2=0,s3=0;
        for(int w=0;w<4;++w){s0+=red[w][0];s1+=red[w][1];s2+=red[w][2];s3+=red[w][3];}
        float tprec=(s0+1.f)/(s1+1.f);
        float tsens=(s2+1.f)/(s3+1.f);
        float cl2=2.f*tprec*tsens/(tprec+tsens+1.f);
        out[0]=1.f-cl2;
    }
}

__global__ void sentinel_kernel(float* out, float v){ out[0]=v; }

extern "C" void kernel_launch(void* const* d_in, const int* in_sizes, int n_in,
                              void* d_out, int out_size, void* d_ws, size_t ws_size,
                              hipStream_t stream) {
    const float* ypred = (const float*)d_in[0];
    const float* ytrue = (const float*)d_in[1];
    float* out = (float*)d_out;

    const size_t need = (size_t)2*N4*sizeof(u16) + (size_t)N4 + (size_t)4*RED_BLOCKS*sizeof(float);
    if (ws_size < need) { sentinel_kernel<<<1,1,0,stream>>>(out,-111111.f); return; }

    u16* EA   = (u16*)d_ws;
    u16* EB   = EA + N4;
    u8*  SKEL = (u8*)(EB + N4);
    float* PART = (float*)(SKEL + N4);

    dim3 grid(WW/TX, HH/TY, 4*NSLAB);   // 2 x 32 x 32 = 2048 blocks = 8/CU

    step_kernel<0><<<grid, NT, 0, stream>>>(nullptr, EB, ypred, ytrue, nullptr, 0);
    step_kernel<1><<<grid, NT, 0, stream>>>(EB, EA, ypred, ytrue, SKEL, 0);

    u16* h = EA;   // e_{t+1}
    u16* a = EB;   // e_t  (overwritten with e_{t+2})
    for (int t = 1; t <= NITER; ++t) {
        if (t < NITER) step_kernel<2><<<grid, NT, 0, stream>>>(h, a, nullptr, nullptr, SKEL, t);
        else           step_kernel<3><<<grid, NT, 0, stream>>>(h, a, nullptr, nullptr, SKEL, t);
        u16* tmp = h; h = a; a = tmp;
    }

    reduce4_kernel<<<RED_BLOCKS, 256, 0, stream>>>(SKEL, ytrue, ypred, PART);
    finalize_kernel<<<1, 256, 0, stream>>>(PART, out);
}

// Round 16
// 1416.325 us; speedup vs baseline: 1.6986x; 1.1783x over previous
//
#include <hip/hip_runtime.h>
#include <hip/hip_fp16.h>
#include <math.h>

#define WW 256
#define HH 256
#define DDP 96
#define HWP (WW*HH)
#define DHW (DDP*HWP)
#define N2 (2*DHW)
#define N4 (4*DHW)
#define TX 128                  // 32 lanes x 2 px-pairs (4 px) per lane
#define TY 8
#define NT 256
#define ZS 12
#define NSLAB (DDP/ZS)          // 8
#define RED_BLOCKS 1024
#define NITER 40
#define RPAIRS 66               // staged u32 pairs per row: px x0-2 .. x0+129
#define NSLOT ((TY+2)*RPAIRS)   // 660 staged pairs per plane
#define NBLK 2048               // (WW/TX)*(HH/TY)*4*NSLAB

typedef unsigned int u32;
typedef unsigned short u16;
typedef unsigned char u8;
typedef __half2 h2;

__device__ __forceinline__ float sigm(float x){return 1.f/(1.f+expf(-x));}
__device__ __forceinline__ int   icl(int v,int hi){return min(max(v,0),hi);}
__device__ __forceinline__ u32 h2u(h2 v){return __builtin_bit_cast(u32,v);}
__device__ __forceinline__ h2  u2h(u32 v){return __builtin_bit_cast(h2,v);}
__device__ __forceinline__ float2 up2(u32 v){return __half22float2(u2h(v));}
__device__ __forceinline__ u32 dn2(float a,float b){return h2u(__floats2half2_rn(a,b));}
__device__ __forceinline__ u32 pmin2(u32 a,u32 b){u32 d;asm("v_pk_min_f16 %0, %1, %2":"=v"(d):"v"(a),"v"(b));return d;}
__device__ __forceinline__ u32 pmax2(u32 a,u32 b){u32 d;asm("v_pk_max_f16 %0, %1, %2":"=v"(d):"v"(a),"v"(b));return d;}
__device__ __forceinline__ u32 psub2(u32 a,u32 b){u32 d;asm("v_pk_add_f16 %0, %1, %2 neg_lo:[0,1] neg_hi:[0,1]":"=v"(d):"v"(a),"v"(b));return d;}
__device__ __forceinline__ u32 pfma2(u32 a,u32 b,u32 c){u32 d;asm("v_pk_fma_f16 %0, %1, %2, %3":"=v"(d):"v"(a),"v"(b),"v"(c));return d;}
__device__ __forceinline__ u32 shpair(u32 hiSrc,u32 loSrc){return __builtin_amdgcn_alignbit(hiSrc,loSrc,16);}
__device__ __forceinline__ u32 sfix(u32 v,int m){
    if (m == 1) v = (v & 0xffffu) | (v << 16);
    else if (m == 2) v = (v >> 16) | (v & 0xffff0000u);
    return v;
}
__device__ __forceinline__ u32 pkrtz(float a,float b){
    return __builtin_bit_cast(u32, __builtin_amdgcn_cvt_pkrtz(a,b));
}
#define INF2P 0x7C007C00u
#define INF2N 0xFC00FC00u
#define C255_2 0x5BF85BF8u      // f16x2 {255,255}

// deterministic stochastic rounding (f32 values in [0,1]) -> u8x4
__device__ __forceinline__ u32 pack_u8_sr(float s0,float s1,float s2,float s3,u32 h){
    float t0 = (float)( h        & 0xff);
    float t1 = (float)((h >>  8) & 0xff);
    float t2 = (float)((h >> 16) & 0xff);
    float t3 = (float)((h >> 24) & 0xff);
    int q0 = min((int)(s0*255.f + (t0+0.5f)*(1.f/256.f)), 255);
    int q1 = min((int)(s1*255.f + (t1+0.5f)*(1.f/256.f)), 255);
    int q2 = min((int)(s2*255.f + (t2+0.5f)*(1.f/256.f)), 255);
    int q3 = min((int)(s3*255.f + (t3+0.5f)*(1.f/256.f)), 255);
    return (u32)q0 | ((u32)q1<<8) | ((u32)q2<<16) | ((u32)q3<<24);
}

// MODE 0: init erode — stage f16(input), write e1 = sigmoid(E(x)) (pred vols) / E(y) (true)
// MODE 1: fused first — ghalo=e1, aimg from fp32 input (sigmoided), skel init (u8 SR); write e2
// MODE 2: fused mid   — skel u8 RMW (packed-f16 S-domain); eaw read then overwritten with e_{t+2}
// MODE 3: fused last  — skel u8 RMW only, no e write
template<int MODE>
__global__ __launch_bounds__(NT) void step_kernel(const u16* __restrict__ ghalo,
                                                  u16* __restrict__ eaw,
                                                  const float* __restrict__ ypred,
                                                  const float* __restrict__ ytrue,
                                                  u8* __restrict__ skel,
                                                  int itno) {
    // XCD-aware bijective swizzle (NBLK % 8 == 0): each XCD owns 4 contiguous
    // xy-layer slabs of one volume -> halo rows / z-boundary planes are L2-local.
    const int bid = blockIdx.x;
    const int swz = (bid & 7) * (NBLK/8) + (bid >> 3);
    const int bx  = swz & 1;
    const int by  = (swz >> 1) & 31;
    const int bz  = swz >> 6;          // 0..31 = vol*NSLAB + slab
    const int vol = bz >> 3;
    const int z0  = (bz & 7) * ZS;

    const int tx = threadIdx.x & 31;
    const int ty = threadIdx.x >> 5;
    const int x0 = bx * TX;
    const int y0 = by * TY;
    const size_t base = (size_t)vol * DHW;
    const int gxc = x0 + 4*tx;
    const int gyc = y0 + ty;
    const size_t co = (size_t)gyc*WW + gxc;

    const float* fin = nullptr;
    bool dosig = false;
    if (MODE == 0 || MODE == 1) {
        if (vol < 2) { fin = ypred + base; dosig = true; }
        else         { fin = ytrue + (size_t)(vol-2)*DHW; }
    }

    __shared__ u32 raw[4][TY+2][RPAIRS];   // 4-deep ring

    // ---- precompute 3 fixed staging slots (hoisted) ----
    const bool s2v = threadIdx.x < (NSLOT - 2*NT);
    u32 lo0, lo1, lo2;
    int md0, md1, md2;
    size_t po0, po1, po2;
    {
        #define SLOTSETUP(K, LO, MD, PO) {                         \
            int idx = threadIdx.x + (K)*NT;                        \
            int r = idx / RPAIRS;                                  \
            int w = idx - r*RPAIRS;                                \
            int gy = icl(y0-1+r, HH-1);                            \
            int gx0 = x0 - 2 + 2*w;                                \
            int m = 0, gx = gx0;                                   \
            if (gx0 < 0) { m = 1; gx = 0; }                        \
            else if (gx0 >= WW) { m = 2; gx = WW-2; }              \
            LO = r*RPAIRS + w; MD = m;                             \
            PO = (size_t)gy*WW + gx; }
        SLOTSETUP(0, lo0, md0, po0)
        SLOTSETUP(1, lo1, md1, po1)
        if (s2v) { SLOTSETUP(2, lo2, md2, po2) } else { lo2 = 0; md2 = 0; po2 = 0; }
        #undef SLOTSETUP
    }

    // slot load helper (plane-relative pointers at plane 0)
    const u16* hq0 = nullptr; const u16* hq1 = nullptr; const u16* hq2 = nullptr;
    const float* fq0 = nullptr; const float* fq1 = nullptr; const float* fq2 = nullptr;
    if (MODE == 0) { fq0 = fin + po0; fq1 = fin + po1; fq2 = fin + po2; }
    else { hq0 = ghalo + base + po0; hq1 = ghalo + base + po1; hq2 = ghalo + base + po2; }

    #define LOADP(Z, V0, V1, V2) {                                           \
        if (MODE == 0) {                                                     \
            float2 f0 = *(const float2*)(fq0 + (size_t)(Z)*HWP); V0 = dn2(f0.x,f0.y); \
            float2 f1 = *(const float2*)(fq1 + (size_t)(Z)*HWP); V1 = dn2(f1.x,f1.y); \
            if (s2v) { float2 f2 = *(const float2*)(fq2 + (size_t)(Z)*HWP); V2 = dn2(f2.x,f2.y); } \
        } else {                                                             \
            V0 = *(const u32*)(hq0 + (size_t)(Z)*HWP);                       \
            V1 = *(const u32*)(hq1 + (size_t)(Z)*HWP);                       \
            if (s2v) V2 = *(const u32*)(hq2 + (size_t)(Z)*HWP);              \
        } }
    #define WRITEP(B, V0, V1, V2) {                                          \
        (&raw[B][0][0])[lo0] = sfix(V0, md0);                                \
        (&raw[B][0][0])[lo1] = sfix(V1, md1);                                \
        if (s2v) (&raw[B][0][0])[lo2] = sfix(V2, md2); }

    // prologue: plane z0-1 written now; plane z0 loaded into vN (written at step z0-1)
    u32 vN0 = 0, vN1 = 0, vN2 = 0;
    if (z0 >= 1) {
        u32 t0 = 0, t1 = 0, t2 = 0;
        LOADP(z0-1, t0, t1, t2)
        LOADP(z0, vN0, vN1, vN2)
        WRITEP((z0-1)&3, t0, t1, t2)
    } else {
        LOADP(z0, vN0, vN1, vN2)
    }
    __syncthreads();

    const int wl = 2*tx;
    u32 n00,n01,n02, n10,n11,n12;
    u32 m00,m01,m02, m10,m11,m12;
    n00=n01=n02=n10=n11=n12=INF2P;
    m00=m01=m02=m10=m11=m12=INF2N;

    uint2 cv_c = make_uint2(0,0), cv_n = make_uint2(0,0);
    u32 sv_c = 0, sv_n = 0;
    float4 fv_c = make_float4(0,0,0,0), fv_n = make_float4(0,0,0,0);

    for (int zi = z0-1; zi <= z0+ZS; ++zi) {
        // depth-2: issue loads for plane zi+2 (consumed at step zi+1's WRITEP)
        const bool far_ok = (zi+2 <= z0+ZS) && (zi+2 < DDP);
        u32 vF0 = 0, vF1 = 0, vF2 = 0;
        if (far_ok) { LOADP(zi+2, vF0, vF1, vF2) }

        // prefetch center/skel for output plane zi (consumed next iter)
        if (MODE != 0 && zi >= z0 && zi < z0+ZS) {
            size_t pidx = base + (size_t)zi*HWP + co;
            if (MODE == 1) {
                fv_n = *(const float4*)(fin + (size_t)zi*HWP + co);
            } else {
                cv_n = *(const uint2*)(eaw + pidx);
                sv_n = *(const u32*)(skel + pidx);
            }
        }

        // separable 3x3 xy window (y-fold then x-fold), packed f16, from ring buf zi&3
        u32 xn0=INF2P, xn1=INF2P, xm0=INF2N, xm1=INF2N;
        if ((unsigned)zi < DDP) {
            const int b = zi & 3;
            uint2 a0 = *(const uint2*)&raw[b][ty  ][wl];
            uint2 b0 = *(const uint2*)&raw[b][ty  ][wl+2];
            uint2 a1 = *(const uint2*)&raw[b][ty+1][wl];
            uint2 b1 = *(const uint2*)&raw[b][ty+1][wl+2];
            uint2 a2 = *(const uint2*)&raw[b][ty+2][wl];
            uint2 b2 = *(const uint2*)&raw[b][ty+2][wl+2];
            u32 vnL  = pmin2(a0.x, pmin2(a1.x, a2.x));
            u32 vnM0 = pmin2(a0.y, pmin2(a1.y, a2.y));
            u32 vnM1 = pmin2(b0.x, pmin2(b1.x, b2.x));
            u32 vnR  = pmin2(b0.y, pmin2(b1.y, b2.y));
            u32 lsn  = shpair(vnM0, vnL);
            u32 rsn  = shpair(vnM1, vnM0);
            u32 rs1n = shpair(vnR,  vnM1);
            xn0 = pmin2(vnM0, pmin2(lsn, rsn));
            xn1 = pmin2(vnM1, pmin2(rsn, rs1n));
            if (MODE != 0) {
                u32 vmL  = pmax2(a0.x, pmax2(a1.x, a2.x));
                u32 vmM0 = pmax2(a0.y, pmax2(a1.y, a2.y));
                u32 vmM1 = pmax2(b0.x, pmax2(b1.x, b2.x));
                u32 vmR  = pmax2(b0.y, pmax2(b1.y, b2.y));
                u32 lsm  = shpair(vmM0, vmL);
                u32 rsm  = shpair(vmM1, vmM0);
                u32 rs1m = shpair(vmR,  vmM1);
                xm0 = pmax2(vmM0, pmax2(lsm, rsm));
                xm1 = pmax2(vmM1, pmax2(rsm, rs1m));
            }
        }
        n00=n01; n01=n02; n02=xn0;  n10=n11; n11=n12; n12=xn1;
        if (MODE != 0) { m00=m01; m01=m02; m02=xm0;  m10=m11; m11=m12; m12=xm1; }

        if (zi >= z0+1) {
            const int zc = zi - 1;
            size_t idx = base + (size_t)zc*HWP + co;
            u32 e0 = pmin2(n00, pmin2(n01, n02));
            u32 e1 = pmin2(n10, pmin2(n11, n12));
            if (MODE == 0) {
                if (dosig) {
                    float2 f0 = up2(e0), f1 = up2(e1);
                    e0 = dn2(sigm(f0.x), sigm(f0.y));
                    e1 = dn2(sigm(f1.x), sigm(f1.y));
                }
                *(uint2*)(eaw + idx) = make_uint2(e0, e1);
            } else if (MODE == 1) {
                float2 mA = up2(pmax2(m00, pmax2(m01, m02)));
                float2 mB = up2(pmax2(m10, pmax2(m11, m12)));
                float av0=fv_c.x, av1=fv_c.y, av2=fv_c.z, av3=fv_c.w;
                if (dosig) { av0=sigm(av0); av1=sigm(av1); av2=sigm(av2); av3=sigm(av3); }
                float d0 = fmaxf(av0 - mA.x, 0.f);
                float d1 = fmaxf(av1 - mA.y, 0.f);
                float d2 = fmaxf(av2 - mB.x, 0.f);
                float d3 = fmaxf(av3 - mB.y, 0.f);
                u32 lin = (u32)(idx >> 2);
                u32 h = lin * 2654435761u + (u32)itno * 0x9E3779B9u;
                *(u32*)(skel + idx) = pack_u8_sr(d0, d1, d2, d3, h);
                *(uint2*)(eaw + idx) = make_uint2(e0, e1);
            } else {
                // packed-f16 S-domain tail: S_new = S + d*(255-S), d = max(av - M3, 0)
                u32 M3p0 = pmax2(m00, pmax2(m01, m02));
                u32 M3p1 = pmax2(m10, pmax2(m11, m12));
                u32 d0p = pmax2(psub2(cv_c.x, M3p0), 0u);
                u32 d1p = pmax2(psub2(cv_c.y, M3p1), 0u);
                u32 Sp0 = pkrtz((float)( sv_c        & 0xff), (float)((sv_c >>  8) & 0xff));
                u32 Sp1 = pkrtz((float)((sv_c >> 16) & 0xff), (float)((sv_c >> 24) & 0xff));
                u32 Sn0 = pfma2(d0p, psub2(C255_2, Sp0), Sp0);
                u32 Sn1 = pfma2(d1p, psub2(C255_2, Sp1), Sp1);
                float2 f0 = up2(Sn0), f1 = up2(Sn1);
                u32 lin = (u32)(idx >> 2);
                u32 h = lin * 2654435761u + (u32)itno * 0x9E3779B9u;
                u32 q0 = (u32)(f0.x + ((float)( h        & 0xff) + 0.5f)*(1.f/256.f));
                u32 q1 = (u32)(f0.y + ((float)((h >>  8) & 0xff) + 0.5f)*(1.f/256.f));
                u32 q2 = (u32)(f1.x + ((float)((h >> 16) & 0xff) + 0.5f)*(1.f/256.f));
                u32 q3 = (u32)(f1.y + ((float)((h >> 24) & 0xff) + 0.5f)*(1.f/256.f));
                *(u32*)(skel + idx) = q0 | (q1<<8) | (q2<<16) | (q3<<24);
                if (MODE != 3) *(uint2*)(eaw + idx) = make_uint2(e0, e1);
            }
        }
        cv_c = cv_n; sv_c = sv_n; fv_c = fv_n;

        // write plane zi+1 (loaded one step ago into vN) into the ring, then barrier
        const bool near_ok = (zi+1 <= z0+ZS) && (zi+1 < DDP);
        if (near_ok) { WRITEP((zi+1)&3, vN0, vN1, vN2) }
        vN0 = vF0; vN1 = vF1; vN2 = vF2;
        __syncthreads();
    }
    #undef LOADP
    #undef WRITEP
}

// ---------------- deterministic 4-sum reduction (vols 0,1 = pred; 2,3 = true) ----------------
__global__ __launch_bounds__(256) void reduce4_kernel(const u8* __restrict__ skel,
                                                      const float* __restrict__ ytrue,
                                                      const float* __restrict__ ypred,
                                                      float* __restrict__ part) {
    const u32* sp = (const u32*)skel;
    const u32* st = (const u32*)(skel + N2);
    const float4* yt = (const float4*)ytrue;
    const float4* yp = (const float4*)ypred;
    float a0=0.f,a1=0.f,a2=0.f,a3=0.f;
    for (int i = blockIdx.x*256 + threadIdx.x; i < N2/4; i += gridDim.x*256) {
        u32 a = sp[i]; u32 b = st[i];
        float4 t = yt[i]; float4 q = yp[i];
        float s0 = (float)( a        & 0xff) * (1.f/255.f);
        float s1 = (float)((a >>  8) & 0xff) * (1.f/255.f);
        float s2 = (float)((a >> 16) & 0xff) * (1.f/255.f);
        float s3 = (float)((a >> 24) & 0xff) * (1.f/255.f);
        float u0 = (float)( b        & 0xff) * (1.f/255.f);
        float u1 = (float)((b >>  8) & 0xff) * (1.f/255.f);
        float u2v= (float)((b >> 16) & 0xff) * (1.f/255.f);
        float u3 = (float)((b >> 24) & 0xff) * (1.f/255.f);
        a0 += s0*t.x + s1*t.y + s2*t.z + s3*t.w;
        a1 += s0 + s1 + s2 + s3;
        a2 += u0*sigm(q.x) + u1*sigm(q.y) + u2v*sigm(q.z) + u3*sigm(q.w);
        a3 += u0 + u1 + u2v + u3;
    }
    for (int off=32; off>0; off>>=1) {
        a0+=__shfl_down(a0,off); a1+=__shfl_down(a1,off);
        a2+=__shfl_down(a2,off); a3+=__shfl_down(a3,off);
    }
    __shared__ float red[4][4];
    int wave = threadIdx.x>>6;
    if ((threadIdx.x&63)==0){red[wave][0]=a0;red[wave][1]=a1;red[wave][2]=a2;red[wave][3]=a3;}
    __syncthreads();
    if (threadIdx.x==0){
        float s0=0,s1=0,s2=0,s3=0;
        for(int w=0;w<4;++w){s0+=red[w][0];s1+=red[w][1];s2+=red[w][2];s3+=red[w][3];}
        part[0*RED_BLOCKS+blockIdx.x]=s0; part[1*RED_BLOCKS+blockIdx.x]=s1;
        part[2*RED_BLOCKS+blockIdx.x]=s2; part[3*RED_BLOCKS+blockIdx.x]=s3;
    }
}

__global__ __launch_bounds__(256) void finalize_kernel(const float* __restrict__ part,
                                                       float* __restrict__ out) {
    float a0=0.f,a1=0.f,a2=0.f,a3=0.f;
    for (int i=threadIdx.x;i<RED_BLOCKS;i+=256){
        a0+=part[0*RED_BLOCKS+i]; a1+=part[1*RED_BLOCKS+i];
        a2+=part[2*RED_BLOCKS+i]; a3+=part[3*RED_BLOCKS+i];
    }
    for (int off=32; off>0; off>>=1){
        a0+=__shfl_down(a0,off); a1+=__shfl_down(a1,off);
        a2+=__shfl_down(a2,off); a3+=__shfl_down(a3,off);
    }
    __shared__ float red[4][4];
    int wave = threadIdx.x>>6;
    if ((threadIdx.x&63)==0){red[wave][0]=a0;red[wave][1]=a1;red[wave][2]=a2;red[wave][3]=a3;}
    __syncthreads();
    if (threadIdx.x==0){
        float s0=0,s1=0,s2=0,s3=0;
        for(int w=0;w<4;++w){s0+=red[w][0];s1+=red[w][1];s2+=red[w][2];s3+=red[w][3];}
        float tprec=(s0+1.f)/(s1+1.f);
        float tsens=(s2+1.f)/(s3+1.f);
        float cl2=2.f*tprec*tsens/(tprec+tsens+1.f);
        out[0]=1.f-cl2;
    }
}

__global__ void sentinel_kernel(float* out, float v){ out[0]=v; }

extern "C" void kernel_launch(void* const* d_in, const int* in_sizes, int n_in,
                              void* d_out, int out_size, void* d_ws, size_t ws_size,
                              hipStream_t stream) {
    const float* ypred = (const float*)d_in[0];
    const float* ytrue = (const float*)d_in[1];
    float* out = (float*)d_out;

    const size_t need = (size_t)2*N4*sizeof(u16) + (size_t)N4 + (size_t)4*RED_BLOCKS*sizeof(float);
    if (ws_size < need) { sentinel_kernel<<<1,1,0,stream>>>(out,-111111.f); return; }

    u16* EA   = (u16*)d_ws;
    u16* EB   = EA + N4;
    u8*  SKEL = (u8*)(EB + N4);
    float* PART = (float*)(SKEL + N4);

    step_kernel<0><<<NBLK, NT, 0, stream>>>(nullptr, EB, ypred, ytrue, nullptr, 0);
    step_kernel<1><<<NBLK, NT, 0, stream>>>(EB, EA, ypred, ytrue, SKEL, 0);

    u16* h = EA;   // e_{t+1}
    u16* a = EB;   // e_t  (overwritten with e_{t+2})
    for (int t = 1; t <= NITER; ++t) {
        if (t < NITER) step_kernel<2><<<NBLK, NT, 0, stream>>>(h, a, nullptr, nullptr, SKEL, t);
        else           step_kernel<3><<<NBLK, NT, 0, stream>>>(h, a, nullptr, nullptr, SKEL, t);
        u16* tmp = h; h = a; a = tmp;
    }

    reduce4_kernel<<<RED_BLOCKS, 256, 0, stream>>>(SKEL, ytrue, ypred, PART);
    finalize_kernel<<<1, 256, 0, stream>>>(PART, out);
}

// Round 17
// 1362.068 us; speedup vs baseline: 1.7663x; 1.0398x over previous
//
#include <hip/hip_runtime.h>
#include <hip/hip_fp16.h>
#include <math.h>

#define WW 256
#define HH 256
#define DDP 96
#define HWP (WW*HH)
#define DHW (DDP*HWP)
#define N2 (2*DHW)
#define N4 (4*DHW)
#define TX 128                  // 32 lanes x 2 px-pairs (4 px) per lane
#define TY 8
#define NT 256
#define ZS 12
#define NSLAB (DDP/ZS)          // 8
#define RED_BLOCKS 1024
#define NITER 40
#define RPAIRS 66               // staged u32 pairs per row: px x0-2 .. x0+129
#define NSLOT ((TY+2)*RPAIRS)   // 660 staged pairs per plane
#define NBLK 2048               // (WW/TX)*(HH/TY)*4*NSLAB

typedef unsigned int u32;
typedef unsigned short u16;
typedef unsigned char u8;
typedef __half2 h2;

__device__ __forceinline__ float sigm(float x){return 1.f/(1.f+expf(-x));}
__device__ __forceinline__ int   icl(int v,int hi){return min(max(v,0),hi);}
__device__ __forceinline__ u32 h2u(h2 v){return __builtin_bit_cast(u32,v);}
__device__ __forceinline__ h2  u2h(u32 v){return __builtin_bit_cast(h2,v);}
__device__ __forceinline__ float2 up2(u32 v){return __half22float2(u2h(v));}
__device__ __forceinline__ u32 dn2(float a,float b){return h2u(__floats2half2_rn(a,b));}
__device__ __forceinline__ u32 pmin2(u32 a,u32 b){u32 d;asm("v_pk_min_f16 %0, %1, %2":"=v"(d):"v"(a),"v"(b));return d;}
__device__ __forceinline__ u32 pmax2(u32 a,u32 b){u32 d;asm("v_pk_max_f16 %0, %1, %2":"=v"(d):"v"(a),"v"(b));return d;}
__device__ __forceinline__ u32 psub2(u32 a,u32 b){u32 d;asm("v_pk_add_f16 %0, %1, %2 neg_lo:[0,1] neg_hi:[0,1]":"=v"(d):"v"(a),"v"(b));return d;}
__device__ __forceinline__ u32 pfma2(u32 a,u32 b,u32 c){u32 d;asm("v_pk_fma_f16 %0, %1, %2, %3":"=v"(d):"v"(a),"v"(b),"v"(c));return d;}
__device__ __forceinline__ u32 shpair(u32 hiSrc,u32 loSrc){return __builtin_amdgcn_alignbit(hiSrc,loSrc,16);}
__device__ __forceinline__ u32 sfix(u32 v,int m){
    if (m == 1) v = (v & 0xffffu) | (v << 16);
    else if (m == 2) v = (v >> 16) | (v & 0xffff0000u);
    return v;
}
__device__ __forceinline__ u32 pkrtz(float a,float b){
    return __builtin_bit_cast(u32, __builtin_amdgcn_cvt_pkrtz(a,b));
}
#define INF2P 0x7C007C00u
#define INF2N 0xFC00FC00u
#define C255_2 0x5BF85BF8u      // f16x2 {255,255}

// deterministic stochastic rounding (f32 values in [0,1]) -> u8x4
__device__ __forceinline__ u32 pack_u8_sr(float s0,float s1,float s2,float s3,u32 h){
    float t0 = (float)( h        & 0xff);
    float t1 = (float)((h >>  8) & 0xff);
    float t2 = (float)((h >> 16) & 0xff);
    float t3 = (float)((h >> 24) & 0xff);
    int q0 = min((int)(s0*255.f + (t0+0.5f)*(1.f/256.f)), 255);
    int q1 = min((int)(s1*255.f + (t1+0.5f)*(1.f/256.f)), 255);
    int q2 = min((int)(s2*255.f + (t2+0.5f)*(1.f/256.f)), 255);
    int q3 = min((int)(s3*255.f + (t3+0.5f)*(1.f/256.f)), 255);
    return (u32)q0 | ((u32)q1<<8) | ((u32)q2<<16) | ((u32)q3<<24);
}

// MODE 0: init erode — stage f16(input), write e1 = sigmoid(E(x)) (pred vols) / E(y) (true)
// MODE 1: fused first — ghalo=e1, aimg from fp32 input (sigmoided), skel init (u8 SR); write e2
// MODE 2: fused mid   — skel u8 RMW (write-skip); eaw read then overwritten (write-skip) w/ e_{t+2}
// MODE 3: fused last  — skel u8 RMW only (write-skip), no e write
template<int MODE>
__global__ __launch_bounds__(NT) void step_kernel(const u16* __restrict__ ghalo,
                                                  u16* __restrict__ eaw,
                                                  const float* __restrict__ ypred,
                                                  const float* __restrict__ ytrue,
                                                  u8* __restrict__ skel,
                                                  int itno) {
    // XCD-aware bijective swizzle (NBLK % 8 == 0)
    const int bid = blockIdx.x;
    const int swz = (bid & 7) * (NBLK/8) + (bid >> 3);
    const int bx  = swz & 1;
    const int by  = (swz >> 1) & 31;
    const int bz  = swz >> 6;          // 0..31 = vol*NSLAB + slab
    const int vol = bz >> 3;
    const int z0  = (bz & 7) * ZS;

    const int tx = threadIdx.x & 31;
    const int ty = threadIdx.x >> 5;
    const int x0 = bx * TX;
    const int y0 = by * TY;
    const size_t base = (size_t)vol * DHW;
    const int gxc = x0 + 4*tx;
    const int gyc = y0 + ty;
    const size_t co = (size_t)gyc*WW + gxc;

    const float* fin = nullptr;
    bool dosig = false;
    if (MODE == 0 || MODE == 1) {
        if (vol < 2) { fin = ypred + base; dosig = true; }
        else         { fin = ytrue + (size_t)(vol-2)*DHW; }
    }

    __shared__ u32 raw[4][TY+2][RPAIRS];   // 4-deep ring

    // ---- precompute 3 fixed staging slots (hoisted) ----
    const bool s2v = threadIdx.x < (NSLOT - 2*NT);
    u32 lo0, lo1, lo2;
    int md0, md1, md2;
    size_t po0, po1, po2;
    {
        #define SLOTSETUP(K, LO, MD, PO) {                         \
            int idx = threadIdx.x + (K)*NT;                        \
            int r = idx / RPAIRS;                                  \
            int w = idx - r*RPAIRS;                                \
            int gy = icl(y0-1+r, HH-1);                            \
            int gx0 = x0 - 2 + 2*w;                                \
            int m = 0, gx = gx0;                                   \
            if (gx0 < 0) { m = 1; gx = 0; }                        \
            else if (gx0 >= WW) { m = 2; gx = WW-2; }              \
            LO = r*RPAIRS + w; MD = m;                             \
            PO = (size_t)gy*WW + gx; }
        SLOTSETUP(0, lo0, md0, po0)
        SLOTSETUP(1, lo1, md1, po1)
        if (s2v) { SLOTSETUP(2, lo2, md2, po2) } else { lo2 = 0; md2 = 0; po2 = 0; }
        #undef SLOTSETUP
    }

    const u16* hq0 = nullptr; const u16* hq1 = nullptr; const u16* hq2 = nullptr;
    const float* fq0 = nullptr; const float* fq1 = nullptr; const float* fq2 = nullptr;
    if (MODE == 0) { fq0 = fin + po0; fq1 = fin + po1; fq2 = fin + po2; }
    else { hq0 = ghalo + base + po0; hq1 = ghalo + base + po1; hq2 = ghalo + base + po2; }

    #define LOADP(Z, V0, V1, V2) {                                           \
        if (MODE == 0) {                                                     \
            float2 f0 = *(const float2*)(fq0 + (size_t)(Z)*HWP); V0 = dn2(f0.x,f0.y); \
            float2 f1 = *(const float2*)(fq1 + (size_t)(Z)*HWP); V1 = dn2(f1.x,f1.y); \
            if (s2v) { float2 f2 = *(const float2*)(fq2 + (size_t)(Z)*HWP); V2 = dn2(f2.x,f2.y); } \
        } else {                                                             \
            V0 = *(const u32*)(hq0 + (size_t)(Z)*HWP);                       \
            V1 = *(const u32*)(hq1 + (size_t)(Z)*HWP);                       \
            if (s2v) V2 = *(const u32*)(hq2 + (size_t)(Z)*HWP);              \
        } }
    #define WRITEP(B, V0, V1, V2) {                                          \
        (&raw[B][0][0])[lo0] = sfix(V0, md0);                                \
        (&raw[B][0][0])[lo1] = sfix(V1, md1);                                \
        if (s2v) (&raw[B][0][0])[lo2] = sfix(V2, md2); }

    u32 vN0 = 0, vN1 = 0, vN2 = 0;
    if (z0 >= 1) {
        u32 t0 = 0, t1 = 0, t2 = 0;
        LOADP(z0-1, t0, t1, t2)
        LOADP(z0, vN0, vN1, vN2)
        WRITEP((z0-1)&3, t0, t1, t2)
    } else {
        LOADP(z0, vN0, vN1, vN2)
    }
    __syncthreads();

    const int wl = 2*tx;
    u32 n00,n01,n02, n10,n11,n12;
    u32 m00,m01,m02, m10,m11,m12;
    n00=n01=n02=n10=n11=n12=INF2P;
    m00=m01=m02=m10=m11=m12=INF2N;

    uint2 cv_c = make_uint2(0,0), cv_n = make_uint2(0,0);
    u32 sv_c = 0, sv_n = 0;
    float4 fv_c = make_float4(0,0,0,0), fv_n = make_float4(0,0,0,0);

    for (int zi = z0-1; zi <= z0+ZS; ++zi) {
        const bool far_ok = (zi+2 <= z0+ZS) && (zi+2 < DDP);
        u32 vF0 = 0, vF1 = 0, vF2 = 0;
        if (far_ok) { LOADP(zi+2, vF0, vF1, vF2) }

        if (MODE != 0 && zi >= z0 && zi < z0+ZS) {
            size_t pidx = base + (size_t)zi*HWP + co;
            if (MODE == 1) {
                fv_n = *(const float4*)(fin + (size_t)zi*HWP + co);
            } else {
                cv_n = *(const uint2*)(eaw + pidx);
                sv_n = *(const u32*)(skel + pidx);
            }
        }

        u32 xn0=INF2P, xn1=INF2P, xm0=INF2N, xm1=INF2N;
        if ((unsigned)zi < DDP) {
            const int b = zi & 3;
            uint2 a0 = *(const uint2*)&raw[b][ty  ][wl];
            uint2 b0 = *(const uint2*)&raw[b][ty  ][wl+2];
            uint2 a1 = *(const uint2*)&raw[b][ty+1][wl];
            uint2 b1 = *(const uint2*)&raw[b][ty+1][wl+2];
            uint2 a2 = *(const uint2*)&raw[b][ty+2][wl];
            uint2 b2 = *(const uint2*)&raw[b][ty+2][wl+2];
            u32 vnL  = pmin2(a0.x, pmin2(a1.x, a2.x));
            u32 vnM0 = pmin2(a0.y, pmin2(a1.y, a2.y));
            u32 vnM1 = pmin2(b0.x, pmin2(b1.x, b2.x));
            u32 vnR  = pmin2(b0.y, pmin2(b1.y, b2.y));
            u32 lsn  = shpair(vnM0, vnL);
            u32 rsn  = shpair(vnM1, vnM0);
            u32 rs1n = shpair(vnR,  vnM1);
            xn0 = pmin2(vnM0, pmin2(lsn, rsn));
            xn1 = pmin2(vnM1, pmin2(rsn, rs1n));
            if (MODE != 0) {
                u32 vmL  = pmax2(a0.x, pmax2(a1.x, a2.x));
                u32 vmM0 = pmax2(a0.y, pmax2(a1.y, a2.y));
                u32 vmM1 = pmax2(b0.x, pmax2(b1.x, b2.x));
                u32 vmR  = pmax2(b0.y, pmax2(b1.y, b2.y));
                u32 lsm  = shpair(vmM0, vmL);
                u32 rsm  = shpair(vmM1, vmM0);
                u32 rs1m = shpair(vmR,  vmM1);
                xm0 = pmax2(vmM0, pmax2(lsm, rsm));
                xm1 = pmax2(vmM1, pmax2(rsm, rs1m));
            }
        }
        n00=n01; n01=n02; n02=xn0;  n10=n11; n11=n12; n12=xn1;
        if (MODE != 0) { m00=m01; m01=m02; m02=xm0;  m10=m11; m11=m12; m12=xm1; }

        if (zi >= z0+1) {
            const int zc = zi - 1;
            size_t idx = base + (size_t)zc*HWP + co;
            u32 e0 = pmin2(n00, pmin2(n01, n02));
            u32 e1 = pmin2(n10, pmin2(n11, n12));
            if (MODE == 0) {
                if (dosig) {
                    float2 f0 = up2(e0), f1 = up2(e1);
                    e0 = dn2(sigm(f0.x), sigm(f0.y));
                    e1 = dn2(sigm(f1.x), sigm(f1.y));
                }
                *(uint2*)(eaw + idx) = make_uint2(e0, e1);
            } else if (MODE == 1) {
                float2 mA = up2(pmax2(m00, pmax2(m01, m02)));
                float2 mB = up2(pmax2(m10, pmax2(m11, m12)));
                float av0=fv_c.x, av1=fv_c.y, av2=fv_c.z, av3=fv_c.w;
                if (dosig) { av0=sigm(av0); av1=sigm(av1); av2=sigm(av2); av3=sigm(av3); }
                float d0 = fmaxf(av0 - mA.x, 0.f);
                float d1 = fmaxf(av1 - mA.y, 0.f);
                float d2 = fmaxf(av2 - mB.x, 0.f);
                float d3 = fmaxf(av3 - mB.y, 0.f);
                u32 lin = (u32)(idx >> 2);
                u32 h = lin * 2654435761u + (u32)itno * 0x9E3779B9u;
                *(u32*)(skel + idx) = pack_u8_sr(d0, d1, d2, d3, h);
                *(uint2*)(eaw + idx) = make_uint2(e0, e1);
            } else {
                // packed-f16 S-domain tail: S_new = S + d*(255-S), d = max(av - M3, 0)
                u32 M3p0 = pmax2(m00, pmax2(m01, m02));
                u32 M3p1 = pmax2(m10, pmax2(m11, m12));
                u32 d0p = pmax2(psub2(cv_c.x, M3p0), 0u);
                u32 d1p = pmax2(psub2(cv_c.y, M3p1), 0u);
                u32 Sp0 = pkrtz((float)( sv_c        & 0xff), (float)((sv_c >>  8) & 0xff));
                u32 Sp1 = pkrtz((float)((sv_c >> 16) & 0xff), (float)((sv_c >> 24) & 0xff));
                u32 Sn0 = pfma2(d0p, psub2(C255_2, Sp0), Sp0);
                u32 Sn1 = pfma2(d1p, psub2(C255_2, Sp1), Sp1);
                float2 f0 = up2(Sn0), f1 = up2(Sn1);
                u32 lin = (u32)(idx >> 2);
                u32 h = lin * 2654435761u + (u32)itno * 0x9E3779B9u;
                u32 q0 = (u32)(f0.x + ((float)( h        & 0xff) + 0.5f)*(1.f/256.f));
                u32 q1 = (u32)(f0.y + ((float)((h >>  8) & 0xff) + 0.5f)*(1.f/256.f));
                u32 q2 = (u32)(f1.x + ((float)((h >> 16) & 0xff) + 0.5f)*(1.f/256.f));
                u32 q3 = (u32)(f1.y + ((float)((h >> 24) & 0xff) + 0.5f)*(1.f/256.f));
                u32 pk = q0 | (q1<<8) | (q2<<16) | (q3<<24);
                if (pk != sv_c) *(u32*)(skel + idx) = pk;          // write-skip (value-identical)
                if (MODE != 3) {
                    if (e0 != cv_c.x || e1 != cv_c.y)
                        *(uint2*)(eaw + idx) = make_uint2(e0, e1); // write-skip (value-identical)
                }
            }
        }
        cv_c = cv_n; sv_c = sv_n; fv_c = fv_n;

        const bool near_ok = (zi+1 <= z0+ZS) && (zi+1 < DDP);
        if (near_ok) { WRITEP((zi+1)&3, vN0, vN1, vN2) }
        vN0 = vF0; vN1 = vF1; vN2 = vF2;
        __syncthreads();
    }
    #undef LOADP
    #undef WRITEP
}

// ---------------- deterministic 4-sum reduction (vols 0,1 = pred; 2,3 = true) ----------------
__global__ __launch_bounds__(256) void reduce4_kernel(const u8* __restrict__ skel,
                                                      const float* __restrict__ ytrue,
                                                      const float* __restrict__ ypred,
                                                      float* __restrict__ part) {
    const u32* sp = (const u32*)skel;
    const u32* st = (const u32*)(skel + N2);
    const float4* yt = (const float4*)ytrue;
    const float4* yp = (const float4*)ypred;
    float a0=0.f,a1=0.f,a2=0.f,a3=0.f;
    for (int i = blockIdx.x*256 + threadIdx.x; i < N2/4; i += gridDim.x*256) {
        u32 a = sp[i]; u32 b = st[i];
        float4 t = yt[i]; float4 q = yp[i];
        float s0 = (float)( a        & 0xff) * (1.f/255.f);
        float s1 = (float)((a >>  8) & 0xff) * (1.f/255.f);
        float s2 = (float)((a >> 16) & 0xff) * (1.f/255.f);
        float s3 = (float)((a >> 24) & 0xff) * (1.f/255.f);
        float u0 = (float)( b        & 0xff) * (1.f/255.f);
        float u1 = (float)((b >>  8) & 0xff) * (1.f/255.f);
        float u2v= (float)((b >> 16) & 0xff) * (1.f/255.f);
        float u3 = (float)((b >> 24) & 0xff) * (1.f/255.f);
        a0 += s0*t.x + s1*t.y + s2*t.z + s3*t.w;
        a1 += s0 + s1 + s2 + s3;
        a2 += u0*sigm(q.x) + u1*sigm(q.y) + u2v*sigm(q.z) + u3*sigm(q.w);
        a3 += u0 + u1 + u2v + u3;
    }
    for (int off=32; off>0; off>>=1) {
        a0+=__shfl_down(a0,off); a1+=__shfl_down(a1,off);
        a2+=__shfl_down(a2,off); a3+=__shfl_down(a3,off);
    }
    __shared__ float red[4][4];
    int wave = threadIdx.x>>6;
    if ((threadIdx.x&63)==0){red[wave][0]=a0;red[wave][1]=a1;red[wave][2]=a2;red[wave][3]=a3;}
    __syncthreads();
    if (threadIdx.x==0){
        float s0=0,s1=0,s2=0,s3=0;
        for(int w=0;w<4;++w){s0+=red[w][0];s1+=red[w][1];s2+=red[w][2];s3+=red[w][3];}
        part[0*RED_BLOCKS+blockIdx.x]=s0; part[1*RED_BLOCKS+blockIdx.x]=s1;
        part[2*RED_BLOCKS+blockIdx.x]=s2; part[3*RED_BLOCKS+blockIdx.x]=s3;
    }
}

__global__ __launch_bounds__(256) void finalize_kernel(const float* __restrict__ part,
                                                       float* __restrict__ out) {
    float a0=0.f,a1=0.f,a2=0.f,a3=0.f;
    for (int i=threadIdx.x;i<RED_BLOCKS;i+=256){
        a0+=part[0*RED_BLOCKS+i]; a1+=part[1*RED_BLOCKS+i];
        a2+=part[2*RED_BLOCKS+i]; a3+=part[3*RED_BLOCKS+i];
    }
    for (int off=32; off>0; off>>=1){
        a0+=__shfl_down(a0,off); a1+=__shfl_down(a1,off);
        a2+=__shfl_down(a2,off); a3+=__shfl_down(a3,off);
    }
    __shared__ float red[4][4];
    int wave = threadIdx.x>>6;
    if ((threadIdx.x&63)==0){red[wave][0]=a0;red[wave][1]=a1;red[wave][2]=a2;red[wave][3]=a3;}
    __syncthreads();
    if (threadIdx.x==0){
        float s0=0,s1=0,s2=0,s3=0;
        for(int w=0;w<4;++w){s0+=red[w][0];s1+=red[w][1];s2+=red[w][2];s3+=red[w][3];}
        float tprec=(s0+1.f)/(s1+1.f);
        float tsens=(s2+1.f)/(s3+1.f);
        float cl2=2.f*tprec*tsens/(tprec+tsens+1.f);
        out[0]=1.f-cl2;
    }
}

__global__ void sentinel_kernel(float* out, float v){ out[0]=v; }

extern "C" void kernel_launch(void* const* d_in, const int* in_sizes, int n_in,
                              void* d_out, int out_size, void* d_ws, size_t ws_size,
                              hipStream_t stream) {
    const float* ypred = (const float*)d_in[0];
    const float* ytrue = (const float*)d_in[1];
    float* out = (float*)d_out;

    const size_t need = (size_t)2*N4*sizeof(u16) + (size_t)N4 + (size_t)4*RED_BLOCKS*sizeof(float);
    if (ws_size < need) { sentinel_kernel<<<1,1,0,stream>>>(out,-111111.f); return; }

    u16* EA   = (u16*)d_ws;
    u16* EB   = EA + N4;
    u8*  SKEL = (u8*)(EB + N4);
    float* PART = (float*)(SKEL + N4);

    step_kernel<0><<<NBLK, NT, 0, stream>>>(nullptr, EB, ypred, ytrue, nullptr, 0);
    step_kernel<1><<<NBLK, NT, 0, stream>>>(EB, EA, ypred, ytrue, SKEL, 0);

    u16* h = EA;   // e_{t+1}
    u16* a = EB;   // e_t  (overwritten with e_{t+2})
    for (int t = 1; t <= NITER; ++t) {
        if (t < NITER) step_kernel<2><<<NBLK, NT, 0, stream>>>(h, a, nullptr, nullptr, SKEL, t);
        else           step_kernel<3><<<NBLK, NT, 0, stream>>>(h, a, nullptr, nullptr, SKEL, t);
        u16* tmp = h; h = a; a = tmp;
    }

    reduce4_kernel<<<RED_BLOCKS, 256, 0, stream>>>(SKEL, ytrue, ypred, PART);
    finalize_kernel<<<1, 256, 0, stream>>>(PART, out);
}